// Round 6
// baseline (520.069 us; speedup 1.0000x reference)
//
#include <hip/hip_runtime.h>
#include <hip/hip_bf16.h>

// Tree-LSTM, depth-15 complete binary tree. N=32767, state 2H=512, gates 2048.
// R9 routing (post-mortem driven):
//  - d13 (B=8192): huge kernel (256 blocks, counted-vmcnt) -- 82.6us measured
//  - d12,d11 (4096,2048): R5b big kernel (2 blocks/CU at d12) -- fixes R8's
//    half-idle regression (d12 80 -> ~43us)
//  - d10..d6 (1024..64): gemm_lstm (d10 grid 512 blocks > big's 128)
//  - d5 (32): gemm_lstm; d4..d0 (<=16): NEW fused tiny_kernel, one launch per
//    level (replaces small_gemm+small_combine pairs; W staged coalesced to LDS)

#define NNODES 32767

typedef __attribute__((ext_vector_type(8))) short bf16x8;
typedef __attribute__((ext_vector_type(4))) float f32x4;

typedef const __attribute__((address_space(1))) void* gptr_t;
typedef __attribute__((address_space(3))) void* lptr_t;

__device__ __forceinline__ float sigf(float x) { return 1.0f / (1.0f + __expf(-x)); }
__device__ __forceinline__ float tanhfast(float x) { return 2.0f / (1.0f + __expf(-2.0f * x)) - 1.0f; }

__device__ __forceinline__ short bf_hi(float x) {
    __hip_bfloat16 h = __float2bfloat16(x);
    return __builtin_bit_cast(short, h);
}
__device__ __forceinline__ float bf_f(short s) {
    __hip_bfloat16 h = __builtin_bit_cast(__hip_bfloat16, s);
    return __bfloat162float(h);
}
__device__ __forceinline__ void split8(const float* src, short* hi, short* lo) {
#pragma unroll
    for (int j = 0; j < 8; ++j) {
        float x = src[j];
        short h = bf_hi(x);
        hi[j] = h;
        lo[j] = bf_hi(x - bf_f(h));
    }
}

// proj[v][r] = dot(emb[v], W_ih[r]) + b_ih[r] + b_hh[r];  grid 256, block 256
__global__ void proj_kernel(const float* __restrict__ emb, const float* __restrict__ W_ih,
                            const float* __restrict__ b_ih, const float* __restrict__ b_hh,
                            float* __restrict__ proj) {
    __shared__ float e[256];
    int v = blockIdx.x >> 3;
    int rc = blockIdx.x & 7;
    int t = threadIdx.x;
    e[t] = emb[v * 256 + t];
    __syncthreads();
    int r = rc * 256 + t;
    const float4* w4 = (const float4*)(W_ih + (size_t)r * 256);
    const float4* e4 = (const float4*)e;
    float acc = 0.f;
#pragma unroll 8
    for (int k = 0; k < 64; ++k) {
        float4 w = w4[k];
        float4 h = e4[k];
        acc += w.x * h.x + w.y * h.y + w.z * h.z + w.w * h.w;
    }
    proj[v * 2048 + r] = acc + b_ih[r] + b_hh[r];
}

// W_hh [2048][512] fp32 -> MFMA B-fragment bf16 hi/lo tables.  grid 512, block 256
__global__ void wpack_kernel(const float* __restrict__ W_hh,
                             short* __restrict__ Whi, short* __restrict__ Wlo) {
    int t = blockIdx.x * 256 + threadIdx.x;
    int lane = t & 63;
    int kt = (t >> 6) & 15;
    int ntile = t >> 10;
    int n = ntile * 16 + (lane & 15);
    int k0 = kt * 32 + (lane >> 4) * 8;
    const float* src = W_hh + (size_t)n * 512 + k0;
    short hi[8], lo[8];
    split8(src, hi, lo);
    *(bf16x8*)(Whi + (size_t)t * 8) = *(bf16x8*)hi;
    *(bf16x8*)(Wlo + (size_t)t * 8) = *(bf16x8*)lo;
}

// leaves: gates = proj[type].  grid 32768, block 256
__global__ void leaf_kernel(const int* __restrict__ types, const float* __restrict__ proj,
                            float* __restrict__ out, float* __restrict__ C256,
                            short* __restrict__ Hsplit) {
    int bi = blockIdx.x;
    int node = 16383 + (bi >> 1);
    int j = ((bi & 1) << 8) + threadIdx.x;
    int tt = types[node];
    const float* p = proj + (size_t)tt * 2048;
    float gi = p[j];
    float gg = p[1024 + j];
    float go = p[1536 + j];
    float cn = sigf(gi) * tanhfast(gg);
    float hn = sigf(go) * tanhfast(cn);
    out[(size_t)node * 512 + j] = hn;
    if ((bi & 1) == 0) {
        C256[(size_t)node * 256 + j] = cn;
        short hi = bf_hi(hn);
        Hsplit[(size_t)node * 512 + j] = hi;
        Hsplit[(size_t)node * 512 + 256 + j] = bf_hi(hn - bf_f(hi));
    }
}

// ---------------------------------------------------------------------------
// d13 only (B = 8192): 512 thr / 8 waves, tile 256 nodes x 256 gate-rows,
// BK=32; 2x64KB LDS dbuf, counted-vmcnt 2-barrier pipeline. 256 blocks.
// ---------------------------------------------------------------------------
__global__ __launch_bounds__(512) void huge_gemm_lstm_kernel(
    const int* __restrict__ a_idx, const int* __restrict__ b_idx,
    const int* __restrict__ types, float* __restrict__ out,
    const float* __restrict__ proj, float* __restrict__ C256,
    short* __restrict__ Hsplit, int node_base) {
    __shared__ __align__(16) short lds[2][32768];  // 128 KB: 2 x 64 chunks x 512
    __shared__ int sA[256], sB[256], sT[256];

    const unsigned WOFF = 16777216u;  // Whi - Hsplit in shorts (ws layout)

    int t = threadIdx.x;
    int lin = blockIdx.x;
    int x = lin >> 3;
    int y = lin & 7;            // y-slice -> XCD pin for the W j-slice
    int node0 = node_base + x * 256;
    int j0 = y * 64;

    if (t < 256) {
        sA[t] = a_idx[node0 + t];
        sB[t] = b_idx[node0 + t];
        sT[t] = types[node0 + t];
    }
    __syncthreads();

    int w = t >> 6, lane = t & 63;
    int wm = w >> 2, wn = w & 3;

    unsigned b0[8], b1[8], sk;
    if (w < 4) {
        sk = 32u;
#pragma unroll
        for (int i = 0; i < 8; ++i) {
            int c = w * 8 + i;
            int mt = c >> 1, part = c & 1;
            int m_loc = mt * 16 + (lane & 15);
            unsigned ks = (unsigned)part * 256u + (unsigned)(lane >> 4) * 8u;
            b0[i] = (unsigned)sA[m_loc] * 512u + ks;
            b1[i] = (unsigned)sB[m_loc] * 512u + ks;
        }
    } else {
        sk = 512u;
#pragma unroll
        for (int i = 0; i < 8; ++i) {
            int cc = (w - 4) * 8 + i;
            int ntl = cc >> 1, part = cc & 1;
            int q = ntl >> 2, sub = ntl & 3;
            unsigned ntg = (unsigned)(q * 32 + y * 4 + sub);
            b0[i] = WOFF + ntg * 8192u + (unsigned)part * 1048576u + (unsigned)lane * 8u;
            b1[i] = b0[i] + 4096u;
        }
    }

    f32x4 acc[8][4];
#pragma unroll
    for (int i = 0; i < 8; ++i)
#pragma unroll
        for (int q = 0; q < 4; ++q) acc[i][q] = (f32x4){0.f, 0.f, 0.f, 0.f};

    auto stage = [&](int kt, int buf) {
#pragma unroll
        for (int i = 0; i < 8; ++i) {
            unsigned off = ((kt < 8) ? b0[i] : b1[i]) + (unsigned)(kt & 7) * sk;
            const short* gsrc = Hsplit + off;
            short* ldst = &lds[buf][(w * 8 + i) * 512];
            __builtin_amdgcn_global_load_lds((gptr_t)gsrc, (lptr_t)ldst, 16, 0, 0);
        }
    };

    auto compute = [&](int buf) {
        const short* L = lds[buf];
        bf16x8 bh[4], bl[4];
#pragma unroll
        for (int q = 0; q < 4; ++q) {
            int ci = 32 + (q * 4 + wn) * 2;
            bh[q] = *(const bf16x8*)&L[ci * 512 + lane * 8];
            bl[q] = *(const bf16x8*)&L[(ci + 1) * 512 + lane * 8];
        }
        __builtin_amdgcn_s_setprio(1);
#pragma unroll
        for (int i = 0; i < 8; ++i) {
            int mt = wm * 8 + i;
            bf16x8 ah = *(const bf16x8*)&L[(mt * 2) * 512 + lane * 8];
            bf16x8 al = *(const bf16x8*)&L[(mt * 2 + 1) * 512 + lane * 8];
#pragma unroll
            for (int q = 0; q < 4; ++q) {
                acc[i][q] = __builtin_amdgcn_mfma_f32_16x16x32_bf16(ah, bh[q], acc[i][q], 0, 0, 0);
                acc[i][q] = __builtin_amdgcn_mfma_f32_16x16x32_bf16(ah, bl[q], acc[i][q], 0, 0, 0);
                acc[i][q] = __builtin_amdgcn_mfma_f32_16x16x32_bf16(al, bh[q], acc[i][q], 0, 0, 0);
            }
        }
        __builtin_amdgcn_s_setprio(0);
    };

    stage(0, 0);
    int cur = 0;
#pragma unroll 1
    for (int kt = 0; kt < 16; ++kt) {
        __builtin_amdgcn_s_barrier();
        if (kt < 15) stage(kt + 1, cur ^ 1);
        if (kt < 15) {
            asm volatile("s_waitcnt vmcnt(8)" ::: "memory");
        } else {
            asm volatile("s_waitcnt vmcnt(0)" ::: "memory");
        }
        __builtin_amdgcn_s_barrier();
        compute(cur);
        cur ^= 1;
    }

    int j = j0 + wn * 16 + (lane & 15);
    bool fh = (j < 256);
    int jc = j & 255;
#pragma unroll
    for (int i = 0; i < 8; ++i) {
        int mrow = wm * 128 + i * 16 + (lane >> 4) * 4;
#pragma unroll
        for (int r = 0; r < 4; ++r) {
            int m_loc = mrow + r;
            int node = node0 + m_loc;
            const float* p = proj + (size_t)sT[m_loc] * 2048 + j;
            float gi = acc[i][0][r] + p[0];
            float gf = acc[i][1][r] + p[512];
            float gg = acc[i][2][r] + p[1024];
            float go = acc[i][3][r] + p[1536];
            int child = fh ? sA[m_loc] : sB[m_loc];
            float c = C256[(size_t)child * 256 + jc];
            float cn = sigf(gf) * c + sigf(gi) * tanhfast(gg);
            float hn = sigf(go) * tanhfast(cn);
            out[(size_t)node * 512 + j] = hn;
            if (fh) {
                C256[(size_t)node * 256 + j] = cn;
                short hi = bf_hi(hn);
                Hsplit[(size_t)node * 512 + j] = hi;
                Hsplit[(size_t)node * 512 + 256 + j] = bf_hi(hn - bf_f(hi));
            }
        }
    }
}

// ---------------------------------------------------------------------------
// Big levels (2048..4096): R5b blocked GEMM + fused LSTM (256 thr, 2 blocks/CU).
// ---------------------------------------------------------------------------
__global__ __launch_bounds__(256) void big_gemm_lstm_kernel(
    const int* __restrict__ a_idx, const int* __restrict__ b_idx,
    const int* __restrict__ types, float* __restrict__ out,
    const short* __restrict__ Whi,  // Wlo = Whi + 1048576 (contiguous in ws)
    const float* __restrict__ proj, float* __restrict__ C256,
    short* __restrict__ Hsplit, int node_base) {
    __shared__ __align__(16) short lds[2][16384];  // 64 KB
    __shared__ int sA[128], sB[128], sT[128];

    int t = threadIdx.x;
    int lin = blockIdx.x;
    int x = lin >> 4;
    int y = (lin & 7) * 2 + ((lin >> 3) & 1);
    int node0 = node_base + x * 128;
    int j0 = y * 32;

    if (t < 128) {
        sA[t] = a_idx[node0 + t];
        sB[t] = b_idx[node0 + t];
        sT[t] = types[node0 + t];
    }
    __syncthreads();

    int w = t >> 6, lane = t & 63;
    int wm = w >> 1, wn = w & 1;

    unsigned b0[8], b1[8];
    const short* tbl;
    unsigned stepk;
    if (w < 2) {
        tbl = Hsplit;
        stepk = 32;
#pragma unroll
        for (int i = 0; i < 8; ++i) {
            int c = w * 8 + i;
            int mt = c >> 1, part = c & 1;
            int m_loc = mt * 16 + (lane & 15);
            unsigned ks = (unsigned)part * 256u + (unsigned)(lane >> 4) * 8u;
            b0[i] = (unsigned)sA[m_loc] * 512u + ks;
            b1[i] = (unsigned)sB[m_loc] * 512u + ks;
        }
    } else {
        tbl = Whi;
        stepk = 512;
#pragma unroll
        for (int i = 0; i < 8; ++i) {
            int cc = (w - 2) * 8 + i;
            int nt = cc >> 1, part = cc & 1;
            int q = nt >> 1, sub = nt & 1;
            unsigned ntg = (unsigned)(q * 32 + y * 2 + sub);
            b0[i] = ntg * 8192u + (unsigned)part * 1048576u + (unsigned)lane * 8u;
            b1[i] = b0[i] + 4096u;
        }
    }

    f32x4 acc[4][4];
#pragma unroll
    for (int i = 0; i < 4; ++i)
#pragma unroll
        for (int q = 0; q < 4; ++q) acc[i][q] = (f32x4){0.f, 0.f, 0.f, 0.f};

    auto stage = [&](int kt, int buf) {
#pragma unroll
        for (int i = 0; i < 8; ++i) {
            unsigned off = ((kt < 8) ? b0[i] : b1[i]) + (unsigned)(kt & 7) * stepk;
            const short* gsrc = tbl + off;
            short* ldst = &lds[buf][(w * 8 + i) * 512];
            __builtin_amdgcn_global_load_lds((gptr_t)gsrc, (lptr_t)ldst, 16, 0, 0);
        }
    };

    auto compute = [&](int buf) {
        const short* L = lds[buf];
        bf16x8 ah[4], al[4];
#pragma unroll
        for (int i = 0; i < 4; ++i) {
            int mt = wm * 4 + i;
            ah[i] = *(const bf16x8*)&L[(mt * 2) * 512 + lane * 8];
            al[i] = *(const bf16x8*)&L[(mt * 2 + 1) * 512 + lane * 8];
        }
#pragma unroll
        for (int q = 0; q < 4; ++q) {
            int nt = q * 2 + wn;
            bf16x8 bh = *(const bf16x8*)&L[(16 + nt * 2) * 512 + lane * 8];
            bf16x8 bl = *(const bf16x8*)&L[(17 + nt * 2) * 512 + lane * 8];
#pragma unroll
            for (int i = 0; i < 4; ++i) {
                acc[i][q] = __builtin_amdgcn_mfma_f32_16x16x32_bf16(ah[i], bh, acc[i][q], 0, 0, 0);
                acc[i][q] = __builtin_amdgcn_mfma_f32_16x16x32_bf16(ah[i], bl, acc[i][q], 0, 0, 0);
                acc[i][q] = __builtin_amdgcn_mfma_f32_16x16x32_bf16(al[i], bh, acc[i][q], 0, 0, 0);
            }
        }
    };

    stage(0, 0);
    __syncthreads();
    for (int kt = 0; kt < 16; ++kt) {
        int cur = kt & 1;
        if (kt < 15) stage(kt + 1, cur ^ 1);
        compute(cur);
        __syncthreads();
    }

    int j = j0 + wn * 16 + (lane & 15);
    bool fh = (j < 256);
    int jc = j & 255;
#pragma unroll
    for (int i = 0; i < 4; ++i) {
        int mrow = wm * 64 + i * 16 + (lane >> 4) * 4;
#pragma unroll
        for (int r = 0; r < 4; ++r) {
            int m_loc = mrow + r;
            int node = node0 + m_loc;
            const float* p = proj + (size_t)sT[m_loc] * 2048 + j;
            float gi = acc[i][0][r] + p[0];
            float gf = acc[i][1][r] + p[512];
            float gg = acc[i][2][r] + p[1024];
            float go = acc[i][3][r] + p[1536];
            int child = fh ? sA[m_loc] : sB[m_loc];
            float c = C256[(size_t)child * 256 + jc];
            float cn = sigf(gf) * c + sigf(gi) * tanhfast(gg);
            float hn = sigf(go) * tanhfast(cn);
            out[(size_t)node * 512 + j] = hn;
            if (fh) {
                C256[(size_t)node * 256 + j] = cn;
                short hi = bf_hi(hn);
                Hsplit[(size_t)node * 512 + j] = hi;
                Hsplit[(size_t)node * 512 + 256 + j] = bf_hi(hn - bf_f(hi));
            }
        }
    }
}

// Fused MFMA GEMM + LSTM (mid levels 32..1024).  32 nodes/block, grid (B/32, J).
__global__ __launch_bounds__(256) void gemm_lstm_kernel(
    const int* __restrict__ a_idx, const int* __restrict__ b_idx,
    const int* __restrict__ types, float* __restrict__ out,
    const short* __restrict__ Whi, const short* __restrict__ Wlo,
    const float* __restrict__ proj, float* __restrict__ C256,
    short* __restrict__ Hsplit, int node_base, int Jc) {
    __shared__ short Ahi[2][16][64][8];   // 32 KB
    __shared__ short Alo[2][16][64][8];   // 32 KB
    __shared__ int sA[32], sB[32], sT[32];
    int t = threadIdx.x;
    int node0 = node_base + blockIdx.x * 32;
    if (t < 32) {
        sA[t] = a_idx[node0 + t];
        sB[t] = b_idx[node0 + t];
        sT[t] = types[node0 + t];
    }
    __syncthreads();

#pragma unroll
    for (int it = 0; it < 8; ++it) {
        int c = it * 256 + t;
        int mt = c >> 10;
        int kt = (c >> 6) & 15;
        int lane = c & 63;
        int m_loc = mt * 16 + (lane & 15);
        int k0 = kt * 32 + (lane >> 4) * 8;
        int child = (k0 < 256) ? sA[m_loc] : sB[m_loc];
        const short* src = Hsplit + (size_t)child * 512 + (k0 & 255);
        *(bf16x8*)&Ahi[mt][kt][lane][0] = *(const bf16x8*)src;
        *(bf16x8*)&Alo[mt][kt][lane][0] = *(const bf16x8*)(src + 256);
    }
    __syncthreads();

    int w = t >> 6;
    int lane = t & 63;
    int jsteps = Jc >> 4;
    int jbase = blockIdx.y * Jc;

    auto epilogue = [&](int j0, f32x4 (&acc)[4][2]) {
        int j = j0 + (lane & 15);
        int jc = j & 255;
        bool fh = (j < 256);
#pragma unroll
        for (int mt = 0; mt < 2; ++mt) {
            int mrow = mt * 16 + (lane >> 4) * 4;
#pragma unroll
            for (int r = 0; r < 4; ++r) {
                int m_loc = mrow + r;
                int node = node0 + m_loc;
                const float* p = proj + (size_t)sT[m_loc] * 2048 + j;
                float gi = acc[0][mt][r] + p[0];
                float gf = acc[1][mt][r] + p[512];
                float gg = acc[2][mt][r] + p[1024];
                float go = acc[3][mt][r] + p[1536];
                int child = fh ? sA[m_loc] : sB[m_loc];
                float c = C256[(size_t)child * 256 + jc];
                float cn = sigf(gf) * c + sigf(gi) * tanhfast(gg);
                float hn = sigf(go) * tanhfast(cn);
                out[(size_t)node * 512 + j] = hn;
                if (fh) {
                    C256[(size_t)node * 256 + j] = cn;
                    short hi = bf_hi(hn);
                    Hsplit[(size_t)node * 512 + j] = hi;
                    Hsplit[(size_t)node * 512 + 256 + j] = bf_hi(hn - bf_f(hi));
                }
            }
        }
    };

    if (jsteps >= 4) {
        for (int js = w; js < jsteps; js += 4) {
            int j0 = jbase + js * 16;
            f32x4 acc[4][2];
#pragma unroll
            for (int q = 0; q < 4; ++q)
#pragma unroll
                for (int mt = 0; mt < 2; ++mt) acc[q][mt] = (f32x4){0.f, 0.f, 0.f, 0.f};
            int nt0 = j0 >> 4;
#pragma unroll 4
            for (int kt = 0; kt < 16; ++kt) {
                bf16x8 ah0 = *(const bf16x8*)&Ahi[0][kt][lane][0];
                bf16x8 al0 = *(const bf16x8*)&Alo[0][kt][lane][0];
                bf16x8 ah1 = *(const bf16x8*)&Ahi[1][kt][lane][0];
                bf16x8 al1 = *(const bf16x8*)&Alo[1][kt][lane][0];
#pragma unroll
                for (int q = 0; q < 4; ++q) {
                    int ntile = q * 32 + nt0;
                    size_t off = ((size_t)(ntile * 16 + kt) * 64 + lane) * 8;
                    bf16x8 bh = *(const bf16x8*)(Whi + off);
                    bf16x8 bl = *(const bf16x8*)(Wlo + off);
                    acc[q][0] = __builtin_amdgcn_mfma_f32_16x16x32_bf16(ah0, bh, acc[q][0], 0, 0, 0);
                    acc[q][0] = __builtin_amdgcn_mfma_f32_16x16x32_bf16(ah0, bl, acc[q][0], 0, 0, 0);
                    acc[q][0] = __builtin_amdgcn_mfma_f32_16x16x32_bf16(al0, bh, acc[q][0], 0, 0, 0);
                    acc[q][1] = __builtin_amdgcn_mfma_f32_16x16x32_bf16(ah1, bh, acc[q][1], 0, 0, 0);
                    acc[q][1] = __builtin_amdgcn_mfma_f32_16x16x32_bf16(ah1, bl, acc[q][1], 0, 0, 0);
                    acc[q][1] = __builtin_amdgcn_mfma_f32_16x16x32_bf16(al1, bh, acc[q][1], 0, 0, 0);
                }
            }
            epilogue(j0, acc);
        }
    } else {
        int js = w & 1;
        int khalf = w >> 1;
        int j0 = jbase + js * 16;
        f32x4 acc[4][2];
#pragma unroll
        for (int q = 0; q < 4; ++q)
#pragma unroll
            for (int mt = 0; mt < 2; ++mt) acc[q][mt] = (f32x4){0.f, 0.f, 0.f, 0.f};
        int nt0 = j0 >> 4;
        int kt0 = khalf * 8;
#pragma unroll 4
        for (int kt = kt0; kt < kt0 + 8; ++kt) {
            bf16x8 ah0 = *(const bf16x8*)&Ahi[0][kt][lane][0];
            bf16x8 al0 = *(const bf16x8*)&Alo[0][kt][lane][0];
            bf16x8 ah1 = *(const bf16x8*)&Ahi[1][kt][lane][0];
            bf16x8 al1 = *(const bf16x8*)&Alo[1][kt][lane][0];
#pragma unroll
            for (int q = 0; q < 4; ++q) {
                int ntile = q * 32 + nt0;
                size_t off = ((size_t)(ntile * 16 + kt) * 64 + lane) * 8;
                bf16x8 bh = *(const bf16x8*)(Whi + off);
                bf16x8 bl = *(const bf16x8*)(Wlo + off);
                acc[q][0] = __builtin_amdgcn_mfma_f32_16x16x32_bf16(ah0, bh, acc[q][0], 0, 0, 0);
                acc[q][0] = __builtin_amdgcn_mfma_f32_16x16x32_bf16(ah0, bl, acc[q][0], 0, 0, 0);
                acc[q][0] = __builtin_amdgcn_mfma_f32_16x16x32_bf16(al0, bh, acc[q][0], 0, 0, 0);
                acc[q][1] = __builtin_amdgcn_mfma_f32_16x16x32_bf16(ah1, bh, acc[q][1], 0, 0, 0);
                acc[q][1] = __builtin_amdgcn_mfma_f32_16x16x32_bf16(ah1, bl, acc[q][1], 0, 0, 0);
                acc[q][1] = __builtin_amdgcn_mfma_f32_16x16x32_bf16(al1, bh, acc[q][1], 0, 0, 0);
            }
        }
        __syncthreads();
        float* xch = (float*)&Ahi[0][0][0][0];
        if (khalf == 1) {
#pragma unroll
            for (int q = 0; q < 4; ++q)
#pragma unroll
                for (int mt = 0; mt < 2; ++mt)
                    *(f32x4*)&xch[(((q * 2 + mt) * 128) + js * 64 + lane) * 4] = acc[q][mt];
        }
        __syncthreads();
        if (khalf == 0) {
#pragma unroll
            for (int q = 0; q < 4; ++q)
#pragma unroll
                for (int mt = 0; mt < 2; ++mt) {
                    f32x4 o = *(const f32x4*)&xch[(((q * 2 + mt) * 128) + js * 64 + lane) * 4];
                    acc[q][mt] += o;
                }
            epilogue(j0, acc);
        }
    }
}

// ---------------------------------------------------------------------------
// Tiny levels (B <= 16): ONE fused kernel per level. grid (B, 8), block 256.
// Block (n = x, cs = y) owns node base+n, cols cs*64..+63 (all 4 gates =
// 256 W rows, my-row m = g*64 + c -> W row g*512 + cs*64 + c).
// Loop 8 chunks of 32 my-rows: stage 64KB W coalesced -> LDS; threads
// (r=t>>3, ks=t&7) partial-dot 64 K; reduce over ks; epilogue by 64 threads.
// fp32 throughout (same numerics as the old small_gemm+small_combine path).
// ---------------------------------------------------------------------------
__global__ __launch_bounds__(256) void tiny_kernel(
    const int* __restrict__ a_idx, const int* __restrict__ b_idx,
    const int* __restrict__ types, const float* __restrict__ W_hh,
    const float* __restrict__ proj, float* __restrict__ C256,
    short* __restrict__ Hsplit, float* __restrict__ out, int node_base) {
    __shared__ float hs[512];          // 2 KB
    __shared__ float Wc[32 * 512];     // 64 KB chunk
    __shared__ float psum[32][9];      // 1.1 KB (pad 8->9)
    __shared__ float gall[256];        // 1 KB: my 256 gate-row results

    int t = threadIdx.x;
    int node = node_base + blockIdx.x;
    int cs = blockIdx.y;
    int na = a_idx[node], nb = b_idx[node];

    // stage h = concat(out[a][0:256], out[b][0:256]) : 128 float4
    if (t < 128) {
        int k = t * 4;
        const float* src = (k < 256) ? (out + (size_t)na * 512 + k)
                                     : (out + (size_t)nb * 512 + (k - 256));
        *(float4*)&hs[k] = *(const float4*)src;
    }
    __syncthreads();

    for (int ch = 0; ch < 8; ++ch) {
        // stage 32 my-rows (m = ch*32 + r): W row g*512 + cs*64 + c, m = g*64+c
        // 16384 floats = 4096 float4; 256 thr x 16 float4, coalesced per row.
        for (int u = 0; u < 16; ++u) {
            int i4 = u * 256 + t;          // float4 index
            int r = i4 >> 7;               // local row 0..31
            int k4 = i4 & 127;
            int m = ch * 32 + r;
            int g = m >> 6, c = m & 63;
            const float* src = W_hh + ((size_t)(g * 512 + cs * 64 + c) * 512) + k4 * 4;
            *(float4*)&Wc[r * 512 + k4 * 4] = *(const float4*)src;
        }
        __syncthreads();
        // partial dot: thread (r = t>>3, ks = t&7) over k = ks*64..+63
        {
            int r = t >> 3, ks = t & 7;
            const float4* w4 = (const float4*)&Wc[r * 512 + ks * 64];
            const float4* h4 = (const float4*)&hs[ks * 64];
            float acc = 0.f;
#pragma unroll
            for (int k = 0; k < 16; ++k) {
                float4 wv = w4[k];
                float4 hv = h4[k];
                acc += wv.x * hv.x + wv.y * hv.y + wv.z * hv.z + wv.w * hv.w;
            }
            psum[r][ks] = acc;
        }
        __syncthreads();
        if (t < 32) {
            float s = psum[t][0];
#pragma unroll
            for (int ks = 1; ks < 8; ++ks) s += psum[t][ks];
            gall[ch * 32 + t] = s;
        }
        __syncthreads();
    }

    // epilogue: thread c < 64 handles col j = cs*64 + c
    if (t < 64) {
        int c = t;
        int j = cs * 64 + c;
        const float* p = proj + (size_t)types[node] * 2048 + j;
        float gi = gall[c] + p[0];
        float gf = gall[64 + c] + p[512];
        float gg = gall[128 + c] + p[1024];
        float go = gall[192 + c] + p[1536];
        int child = (j < 256) ? na : nb;
        float cc = C256[(size_t)child * 256 + (j & 255)];
        float cn = sigf(gf) * cc + sigf(gi) * tanhfast(gg);
        float hn = sigf(go) * tanhfast(cn);
        out[(size_t)node * 512 + j] = hn;
        if (j < 256) {
            C256[(size_t)node * 256 + j] = cn;
            short hi = bf_hi(hn);
            Hsplit[(size_t)node * 512 + j] = hi;
            Hsplit[(size_t)node * 512 + 256 + j] = bf_hi(hn - bf_f(hi));
        }
    }
}

extern "C" void kernel_launch(void* const* d_in, const int* in_sizes, int n_in,
                              void* d_out, int out_size, void* d_ws, size_t ws_size,
                              hipStream_t stream) {
    const int* types = (const int*)d_in[0];
    const int* a_idx = (const int*)d_in[1];
    const int* b_idx = (const int*)d_in[2];
    const float* emb = (const float*)d_in[3];
    const float* W_ih = (const float*)d_in[4];
    const float* W_hh = (const float*)d_in[5];
    const float* b_ih = (const float*)d_in[6];
    const float* b_hh = (const float*)d_in[7];
    float* out = (float*)d_out;

    float* ws = (float*)d_ws;
    float* proj = ws;                               // 65536 floats (256 KB)
    float* C256 = ws + 65536;                       // 8388352 floats (32 MB)
    short* Hsplit = (short*)(C256 + 8388352);       // 32767*512 shorts (32 MB)
    short* Whi = Hsplit + 16777216;                 // 2048*512 shorts (2 MB); MUST stay
    short* Wlo = Whi + 1048576;                     // contiguous after Hsplit (WOFF)
    // total ws use ~68.3 MB

    proj_kernel<<<256, 256, 0, stream>>>(emb, W_ih, b_ih, b_hh, proj);
    wpack_kernel<<<512, 256, 0, stream>>>(W_hh, Whi, Wlo);
    leaf_kernel<<<32768, 256, 0, stream>>>(types, proj, out, C256, Hsplit);

    for (int d = 13; d >= 0; --d) {
        int base = (1 << d) - 1;
        int B = 1 << d;
        if (B >= 8192) {
            huge_gemm_lstm_kernel<<<(B / 256) * 8, 512, 0, stream>>>(
                a_idx, b_idx, types, out, proj, C256, Hsplit, base);
        } else if (B >= 2048) {
            int X = B / 128;
            big_gemm_lstm_kernel<<<X * 16, 256, 0, stream>>>(
                a_idx, b_idx, types, out, Whi, proj, C256, Hsplit, base);
        } else if (B >= 32) {
            int bx = B / 32;
            int J = 2;
            while (bx * J < 512 && J < 16) J <<= 1;
            gemm_lstm_kernel<<<dim3(bx, J), 256, 0, stream>>>(
                a_idx, b_idx, types, out, Whi, Wlo, proj, C256, Hsplit, base, 512 / J);
        } else {
            tiny_kernel<<<dim3(B, 8), 256, 0, stream>>>(
                a_idx, b_idx, types, W_hh, proj, C256, Hsplit, out, base);
        }
    }
}

// Round 7
// 415.877 us; speedup vs baseline: 1.2505x; 1.2505x over previous
//
#include <hip/hip_runtime.h>
#include <hip/hip_bf16.h>

// Tree-LSTM, depth-15 complete binary tree. N=32767, state 2H=512, gates 2048.
// R10: routing = R5b exactly (best measured, 418us), EXCEPT d13 uses the huge
// kernel with REFORMED A-staging:
//  - old: A staged as 16B/lane gathers -> 64 cache lines per 1KB instruction
//  - new: 8 rows x 128B contiguous (hi64+lo64) per instruction -> 16 lines (min)
//  - LDS chunk = [8 rows][8 slots x 16B], source-side XOR swizzle j = slot ^ row
//    (linear global_load_lds dest + inverse-swizzled source + swizzled read)
//  - theory: all schedules were L2-request-rate bound (~4 cyc/line); lines/step
//    2560 -> 1024 => d13 ~82.6 -> ~35-45us
// d12..d10: R5b big kernel; d9..d5: gemm_lstm; d4..d0: small_gemm+small_combine.

#define NNODES 32767

typedef __attribute__((ext_vector_type(8))) short bf16x8;
typedef __attribute__((ext_vector_type(4))) float f32x4;

typedef const __attribute__((address_space(1))) void* gptr_t;
typedef __attribute__((address_space(3))) void* lptr_t;

__device__ __forceinline__ float sigf(float x) { return 1.0f / (1.0f + __expf(-x)); }
__device__ __forceinline__ float tanhfast(float x) { return 2.0f / (1.0f + __expf(-2.0f * x)) - 1.0f; }

__device__ __forceinline__ short bf_hi(float x) {
    __hip_bfloat16 h = __float2bfloat16(x);
    return __builtin_bit_cast(short, h);
}
__device__ __forceinline__ float bf_f(short s) {
    __hip_bfloat16 h = __builtin_bit_cast(__hip_bfloat16, s);
    return __bfloat162float(h);
}
__device__ __forceinline__ void split8(const float* src, short* hi, short* lo) {
#pragma unroll
    for (int j = 0; j < 8; ++j) {
        float x = src[j];
        short h = bf_hi(x);
        hi[j] = h;
        lo[j] = bf_hi(x - bf_f(h));
    }
}

// proj[v][r] = dot(emb[v], W_ih[r]) + b_ih[r] + b_hh[r];  grid 256, block 256
__global__ void proj_kernel(const float* __restrict__ emb, const float* __restrict__ W_ih,
                            const float* __restrict__ b_ih, const float* __restrict__ b_hh,
                            float* __restrict__ proj) {
    __shared__ float e[256];
    int v = blockIdx.x >> 3;
    int rc = blockIdx.x & 7;
    int t = threadIdx.x;
    e[t] = emb[v * 256 + t];
    __syncthreads();
    int r = rc * 256 + t;
    const float4* w4 = (const float4*)(W_ih + (size_t)r * 256);
    const float4* e4 = (const float4*)e;
    float acc = 0.f;
#pragma unroll 8
    for (int k = 0; k < 64; ++k) {
        float4 w = w4[k];
        float4 h = e4[k];
        acc += w.x * h.x + w.y * h.y + w.z * h.z + w.w * h.w;
    }
    proj[v * 2048 + r] = acc + b_ih[r] + b_hh[r];
}

// W_hh [2048][512] fp32 -> MFMA B-fragment bf16 hi/lo tables.  grid 512, block 256
__global__ void wpack_kernel(const float* __restrict__ W_hh,
                             short* __restrict__ Whi, short* __restrict__ Wlo) {
    int t = blockIdx.x * 256 + threadIdx.x;
    int lane = t & 63;
    int kt = (t >> 6) & 15;
    int ntile = t >> 10;
    int n = ntile * 16 + (lane & 15);
    int k0 = kt * 32 + (lane >> 4) * 8;
    const float* src = W_hh + (size_t)n * 512 + k0;
    short hi[8], lo[8];
    split8(src, hi, lo);
    *(bf16x8*)(Whi + (size_t)t * 8) = *(bf16x8*)hi;
    *(bf16x8*)(Wlo + (size_t)t * 8) = *(bf16x8*)lo;
}

// leaves: gates = proj[type].  grid 32768, block 256
__global__ void leaf_kernel(const int* __restrict__ types, const float* __restrict__ proj,
                            float* __restrict__ out, float* __restrict__ C256,
                            short* __restrict__ Hsplit) {
    int bi = blockIdx.x;
    int node = 16383 + (bi >> 1);
    int j = ((bi & 1) << 8) + threadIdx.x;
    int tt = types[node];
    const float* p = proj + (size_t)tt * 2048;
    float gi = p[j];
    float gg = p[1024 + j];
    float go = p[1536 + j];
    float cn = sigf(gi) * tanhfast(gg);
    float hn = sigf(go) * tanhfast(cn);
    out[(size_t)node * 512 + j] = hn;
    if ((bi & 1) == 0) {
        C256[(size_t)node * 256 + j] = cn;
        short hi = bf_hi(hn);
        Hsplit[(size_t)node * 512 + j] = hi;
        Hsplit[(size_t)node * 512 + 256 + j] = bf_hi(hn - bf_f(hi));
    }
}

// ---------------------------------------------------------------------------
// d13 (B = 8192): 512 thr / 8 waves, tile 256 nodes x 256 gate-rows, BK=32;
// 2x64KB LDS dbuf, counted-vmcnt 2-barrier pipeline. 256 blocks.
// REFORMED A-staging: chunk ca (1KB) = rows ca*8..+8, per row 128B (hi64+lo64)
// of this kt-slice, contiguous loads; piece at slot (r, js) is j = js ^ r
// (j = p*4+s). Read: slot = r*8 + ((p*4+s) ^ r). W path unchanged.
// ---------------------------------------------------------------------------
__global__ __launch_bounds__(512) void huge_gemm_lstm_kernel(
    const int* __restrict__ a_idx, const int* __restrict__ b_idx,
    const int* __restrict__ types, float* __restrict__ out,
    const float* __restrict__ proj, float* __restrict__ C256,
    short* __restrict__ Hsplit, int node_base) {
    __shared__ __align__(16) short lds[2][32768];  // 128 KB: 2 x 64 chunks x 512
    __shared__ int sA[256], sB[256], sT[256];

    const unsigned WOFF = 16777216u;  // Whi - Hsplit in shorts (ws layout)

    int t = threadIdx.x;
    int lin = blockIdx.x;
    int x = lin >> 3;
    int y = lin & 7;            // y-slice -> XCD pin for the W j-slice
    int node0 = node_base + x * 256;
    int j0 = y * 64;

    if (t < 256) {
        sA[t] = a_idx[node0 + t];
        sB[t] = b_idx[node0 + t];
        sT[t] = types[node0 + t];
    }
    __syncthreads();

    int w = t >> 6, lane = t & 63;
    int wm = w >> 2, wn = w & 3;

    // Staging bases (short offsets rel. Hsplit). Chunk c = w*8+i.
    // Waves 0-3: A chunks ca = c (0..31): lane l -> row ca*8 + (l>>3),
    //   piece j = (l&7) ^ (l>>3), p = j>>2, s = j&3;
    //   src = child*512 + p*256 + s*8 (+ krel*32 per step).
    // Waves 4-7: W chunks (cc = c-32): unchanged linear fragments.
    unsigned b0[8], b1[8], sk;
    if (w < 4) {
        sk = 32u;
#pragma unroll
        for (int i = 0; i < 8; ++i) {
            int ca = w * 8 + i;
            int rl = lane >> 3;              // row within chunk 0..7
            int r_loc = ca * 8 + rl;         // row index 0..255
            int j = (lane & 7) ^ rl;         // swizzled piece id
            unsigned ks = (unsigned)(j >> 2) * 256u + (unsigned)(j & 3) * 8u;
            b0[i] = (unsigned)sA[r_loc] * 512u + ks;
            b1[i] = (unsigned)sB[r_loc] * 512u + ks;
        }
    } else {
        sk = 512u;
#pragma unroll
        for (int i = 0; i < 8; ++i) {
            int cc = (w - 4) * 8 + i;
            int ntl = cc >> 1, part = cc & 1;
            int q = ntl >> 2, sub = ntl & 3;
            unsigned ntg = (unsigned)(q * 32 + y * 4 + sub);
            b0[i] = WOFF + ntg * 8192u + (unsigned)part * 1048576u + (unsigned)lane * 8u;
            b1[i] = b0[i] + 4096u;
        }
    }

    f32x4 acc[8][4];
#pragma unroll
    for (int i = 0; i < 8; ++i)
#pragma unroll
        for (int q = 0; q < 4; ++q) acc[i][q] = (f32x4){0.f, 0.f, 0.f, 0.f};

    auto stage = [&](int kt, int buf) {
#pragma unroll
        for (int i = 0; i < 8; ++i) {
            unsigned off = ((kt < 8) ? b0[i] : b1[i]) + (unsigned)(kt & 7) * sk;
            const short* gsrc = Hsplit + off;
            short* ldst = &lds[buf][(w * 8 + i) * 512];
            __builtin_amdgcn_global_load_lds((gptr_t)gsrc, (lptr_t)ldst, 16, 0, 0);
        }
    };

    auto compute = [&](int buf) {
        const short* L = lds[buf];
        bf16x8 bh[4], bl[4];
#pragma unroll
        for (int q = 0; q < 4; ++q) {
            int ci = 32 + (q * 4 + wn) * 2;
            bh[q] = *(const bf16x8*)&L[ci * 512 + lane * 8];
            bl[q] = *(const bf16x8*)&L[(ci + 1) * 512 + lane * 8];
        }
        int s = lane >> 4;        // k-sub 0..3
        __builtin_amdgcn_s_setprio(1);
#pragma unroll
        for (int i = 0; i < 8; ++i) {
            int m_loc = wm * 128 + i * 16 + (lane & 15);
            int ch = m_loc >> 3;
            int r = m_loc & 7;
            const short* base = L + ch * 512 + r * 64;  // r*8 slots *8 shorts
            bf16x8 ah = *(const bf16x8*)&base[((s) ^ r) * 8];
            bf16x8 al = *(const bf16x8*)&base[((4 + s) ^ r) * 8];
#pragma unroll
            for (int q = 0; q < 4; ++q) {
                acc[i][q] = __builtin_amdgcn_mfma_f32_16x16x32_bf16(ah, bh[q], acc[i][q], 0, 0, 0);
                acc[i][q] = __builtin_amdgcn_mfma_f32_16x16x32_bf16(ah, bl[q], acc[i][q], 0, 0, 0);
                acc[i][q] = __builtin_amdgcn_mfma_f32_16x16x32_bf16(al, bh[q], acc[i][q], 0, 0, 0);
            }
        }
        __builtin_amdgcn_s_setprio(0);
    };

    stage(0, 0);
    int cur = 0;
#pragma unroll 1
    for (int kt = 0; kt < 16; ++kt) {
        __builtin_amdgcn_s_barrier();
        if (kt < 15) stage(kt + 1, cur ^ 1);
        if (kt < 15) {
            asm volatile("s_waitcnt vmcnt(8)" ::: "memory");
        } else {
            asm volatile("s_waitcnt vmcnt(0)" ::: "memory");
        }
        __builtin_amdgcn_s_barrier();
        compute(cur);
        cur ^= 1;
    }

    int j = j0 + wn * 16 + (lane & 15);
    bool fh = (j < 256);
    int jc = j & 255;
#pragma unroll
    for (int i = 0; i < 8; ++i) {
        int mrow = wm * 128 + i * 16 + (lane >> 4) * 4;
#pragma unroll
        for (int r = 0; r < 4; ++r) {
            int m_loc = mrow + r;
            int node = node0 + m_loc;
            const float* p = proj + (size_t)sT[m_loc] * 2048 + j;
            float gi = acc[i][0][r] + p[0];
            float gf = acc[i][1][r] + p[512];
            float gg = acc[i][2][r] + p[1024];
            float go = acc[i][3][r] + p[1536];
            int child = fh ? sA[m_loc] : sB[m_loc];
            float c = C256[(size_t)child * 256 + jc];
            float cn = sigf(gf) * c + sigf(gi) * tanhfast(gg);
            float hn = sigf(go) * tanhfast(cn);
            out[(size_t)node * 512 + j] = hn;
            if (fh) {
                C256[(size_t)node * 256 + j] = cn;
                short hi = bf_hi(hn);
                Hsplit[(size_t)node * 512 + j] = hi;
                Hsplit[(size_t)node * 512 + 256 + j] = bf_hi(hn - bf_f(hi));
            }
        }
    }
}

// ---------------------------------------------------------------------------
// Big levels (1024..4096): R5b blocked GEMM + fused LSTM (256 thr, 2 blocks/CU).
// ---------------------------------------------------------------------------
__global__ __launch_bounds__(256) void big_gemm_lstm_kernel(
    const int* __restrict__ a_idx, const int* __restrict__ b_idx,
    const int* __restrict__ types, float* __restrict__ out,
    const short* __restrict__ Whi,  // Wlo = Whi + 1048576 (contiguous in ws)
    const float* __restrict__ proj, float* __restrict__ C256,
    short* __restrict__ Hsplit, int node_base) {
    __shared__ __align__(16) short lds[2][16384];  // 64 KB
    __shared__ int sA[128], sB[128], sT[128];

    int t = threadIdx.x;
    int lin = blockIdx.x;
    int x = lin >> 4;
    int y = (lin & 7) * 2 + ((lin >> 3) & 1);
    int node0 = node_base + x * 128;
    int j0 = y * 32;

    if (t < 128) {
        sA[t] = a_idx[node0 + t];
        sB[t] = b_idx[node0 + t];
        sT[t] = types[node0 + t];
    }
    __syncthreads();

    int w = t >> 6, lane = t & 63;
    int wm = w >> 1, wn = w & 1;

    unsigned b0[8], b1[8];
    const short* tbl;
    unsigned stepk;
    if (w < 2) {
        tbl = Hsplit;
        stepk = 32;
#pragma unroll
        for (int i = 0; i < 8; ++i) {
            int c = w * 8 + i;
            int mt = c >> 1, part = c & 1;
            int m_loc = mt * 16 + (lane & 15);
            unsigned ks = (unsigned)part * 256u + (unsigned)(lane >> 4) * 8u;
            b0[i] = (unsigned)sA[m_loc] * 512u + ks;
            b1[i] = (unsigned)sB[m_loc] * 512u + ks;
        }
    } else {
        tbl = Whi;
        stepk = 512;
#pragma unroll
        for (int i = 0; i < 8; ++i) {
            int cc = (w - 2) * 8 + i;
            int nt = cc >> 1, part = cc & 1;
            int q = nt >> 1, sub = nt & 1;
            unsigned ntg = (unsigned)(q * 32 + y * 2 + sub);
            b0[i] = ntg * 8192u + (unsigned)part * 1048576u + (unsigned)lane * 8u;
            b1[i] = b0[i] + 4096u;
        }
    }

    f32x4 acc[4][4];
#pragma unroll
    for (int i = 0; i < 4; ++i)
#pragma unroll
        for (int q = 0; q < 4; ++q) acc[i][q] = (f32x4){0.f, 0.f, 0.f, 0.f};

    auto stage = [&](int kt, int buf) {
#pragma unroll
        for (int i = 0; i < 8; ++i) {
            unsigned off = ((kt < 8) ? b0[i] : b1[i]) + (unsigned)(kt & 7) * stepk;
            const short* gsrc = tbl + off;
            short* ldst = &lds[buf][(w * 8 + i) * 512];
            __builtin_amdgcn_global_load_lds((gptr_t)gsrc, (lptr_t)ldst, 16, 0, 0);
        }
    };

    auto compute = [&](int buf) {
        const short* L = lds[buf];
        bf16x8 ah[4], al[4];
#pragma unroll
        for (int i = 0; i < 4; ++i) {
            int mt = wm * 4 + i;
            ah[i] = *(const bf16x8*)&L[(mt * 2) * 512 + lane * 8];
            al[i] = *(const bf16x8*)&L[(mt * 2 + 1) * 512 + lane * 8];
        }
#pragma unroll
        for (int q = 0; q < 4; ++q) {
            int nt = q * 2 + wn;
            bf16x8 bh = *(const bf16x8*)&L[(16 + nt * 2) * 512 + lane * 8];
            bf16x8 bl = *(const bf16x8*)&L[(17 + nt * 2) * 512 + lane * 8];
#pragma unroll
            for (int i = 0; i < 4; ++i) {
                acc[i][q] = __builtin_amdgcn_mfma_f32_16x16x32_bf16(ah[i], bh, acc[i][q], 0, 0, 0);
                acc[i][q] = __builtin_amdgcn_mfma_f32_16x16x32_bf16(ah[i], bl, acc[i][q], 0, 0, 0);
                acc[i][q] = __builtin_amdgcn_mfma_f32_16x16x32_bf16(al[i], bh, acc[i][q], 0, 0, 0);
            }
        }
    };

    stage(0, 0);
    __syncthreads();
    for (int kt = 0; kt < 16; ++kt) {
        int cur = kt & 1;
        if (kt < 15) stage(kt + 1, cur ^ 1);
        compute(cur);
        __syncthreads();
    }

    int j = j0 + wn * 16 + (lane & 15);
    bool fh = (j < 256);
    int jc = j & 255;
#pragma unroll
    for (int i = 0; i < 4; ++i) {
        int mrow = wm * 64 + i * 16 + (lane >> 4) * 4;
#pragma unroll
        for (int r = 0; r < 4; ++r) {
            int m_loc = mrow + r;
            int node = node0 + m_loc;
            const float* p = proj + (size_t)sT[m_loc] * 2048 + j;
            float gi = acc[i][0][r] + p[0];
            float gf = acc[i][1][r] + p[512];
            float gg = acc[i][2][r] + p[1024];
            float go = acc[i][3][r] + p[1536];
            int child = fh ? sA[m_loc] : sB[m_loc];
            float c = C256[(size_t)child * 256 + jc];
            float cn = sigf(gf) * c + sigf(gi) * tanhfast(gg);
            float hn = sigf(go) * tanhfast(cn);
            out[(size_t)node * 512 + j] = hn;
            if (fh) {
                C256[(size_t)node * 256 + j] = cn;
                short hi = bf_hi(hn);
                Hsplit[(size_t)node * 512 + j] = hi;
                Hsplit[(size_t)node * 512 + 256 + j] = bf_hi(hn - bf_f(hi));
            }
        }
    }
}

// Fused MFMA GEMM + LSTM (mid levels 32..512).  32 nodes/block, grid (B/32, J).
__global__ __launch_bounds__(256) void gemm_lstm_kernel(
    const int* __restrict__ a_idx, const int* __restrict__ b_idx,
    const int* __restrict__ types, float* __restrict__ out,
    const short* __restrict__ Whi, const short* __restrict__ Wlo,
    const float* __restrict__ proj, float* __restrict__ C256,
    short* __restrict__ Hsplit, int node_base, int Jc) {
    __shared__ short Ahi[2][16][64][8];   // 32 KB
    __shared__ short Alo[2][16][64][8];   // 32 KB
    __shared__ int sA[32], sB[32], sT[32];
    int t = threadIdx.x;
    int node0 = node_base + blockIdx.x * 32;
    if (t < 32) {
        sA[t] = a_idx[node0 + t];
        sB[t] = b_idx[node0 + t];
        sT[t] = types[node0 + t];
    }
    __syncthreads();

#pragma unroll
    for (int it = 0; it < 8; ++it) {
        int c = it * 256 + t;
        int mt = c >> 10;
        int kt = (c >> 6) & 15;
        int lane = c & 63;
        int m_loc = mt * 16 + (lane & 15);
        int k0 = kt * 32 + (lane >> 4) * 8;
        int child = (k0 < 256) ? sA[m_loc] : sB[m_loc];
        const short* src = Hsplit + (size_t)child * 512 + (k0 & 255);
        *(bf16x8*)&Ahi[mt][kt][lane][0] = *(const bf16x8*)src;
        *(bf16x8*)&Alo[mt][kt][lane][0] = *(const bf16x8*)(src + 256);
    }
    __syncthreads();

    int w = t >> 6;
    int lane = t & 63;
    int jsteps = Jc >> 4;
    int jbase = blockIdx.y * Jc;

    auto epilogue = [&](int j0, f32x4 (&acc)[4][2]) {
        int j = j0 + (lane & 15);
        int jc = j & 255;
        bool fh = (j < 256);
#pragma unroll
        for (int mt = 0; mt < 2; ++mt) {
            int mrow = mt * 16 + (lane >> 4) * 4;
#pragma unroll
            for (int r = 0; r < 4; ++r) {
                int m_loc = mrow + r;
                int node = node0 + m_loc;
                const float* p = proj + (size_t)sT[m_loc] * 2048 + j;
                float gi = acc[0][mt][r] + p[0];
                float gf = acc[1][mt][r] + p[512];
                float gg = acc[2][mt][r] + p[1024];
                float go = acc[3][mt][r] + p[1536];
                int child = fh ? sA[m_loc] : sB[m_loc];
                float c = C256[(size_t)child * 256 + jc];
                float cn = sigf(gf) * c + sigf(gi) * tanhfast(gg);
                float hn = sigf(go) * tanhfast(cn);
                out[(size_t)node * 512 + j] = hn;
                if (fh) {
                    C256[(size_t)node * 256 + j] = cn;
                    short hi = bf_hi(hn);
                    Hsplit[(size_t)node * 512 + j] = hi;
                    Hsplit[(size_t)node * 512 + 256 + j] = bf_hi(hn - bf_f(hi));
                }
            }
        }
    };

    if (jsteps >= 4) {
        for (int js = w; js < jsteps; js += 4) {
            int j0 = jbase + js * 16;
            f32x4 acc[4][2];
#pragma unroll
            for (int q = 0; q < 4; ++q)
#pragma unroll
                for (int mt = 0; mt < 2; ++mt) acc[q][mt] = (f32x4){0.f, 0.f, 0.f, 0.f};
            int nt0 = j0 >> 4;
#pragma unroll 4
            for (int kt = 0; kt < 16; ++kt) {
                bf16x8 ah0 = *(const bf16x8*)&Ahi[0][kt][lane][0];
                bf16x8 al0 = *(const bf16x8*)&Alo[0][kt][lane][0];
                bf16x8 ah1 = *(const bf16x8*)&Ahi[1][kt][lane][0];
                bf16x8 al1 = *(const bf16x8*)&Alo[1][kt][lane][0];
#pragma unroll
                for (int q = 0; q < 4; ++q) {
                    int ntile = q * 32 + nt0;
                    size_t off = ((size_t)(ntile * 16 + kt) * 64 + lane) * 8;
                    bf16x8 bh = *(const bf16x8*)(Whi + off);
                    bf16x8 bl = *(const bf16x8*)(Wlo + off);
                    acc[q][0] = __builtin_amdgcn_mfma_f32_16x16x32_bf16(ah0, bh, acc[q][0], 0, 0, 0);
                    acc[q][0] = __builtin_amdgcn_mfma_f32_16x16x32_bf16(ah0, bl, acc[q][0], 0, 0, 0);
                    acc[q][0] = __builtin_amdgcn_mfma_f32_16x16x32_bf16(al0, bh, acc[q][0], 0, 0, 0);
                    acc[q][1] = __builtin_amdgcn_mfma_f32_16x16x32_bf16(ah1, bh, acc[q][1], 0, 0, 0);
                    acc[q][1] = __builtin_amdgcn_mfma_f32_16x16x32_bf16(ah1, bl, acc[q][1], 0, 0, 0);
                    acc[q][1] = __builtin_amdgcn_mfma_f32_16x16x32_bf16(al1, bh, acc[q][1], 0, 0, 0);
                }
            }
            epilogue(j0, acc);
        }
    } else {
        int js = w & 1;
        int khalf = w >> 1;
        int j0 = jbase + js * 16;
        f32x4 acc[4][2];
#pragma unroll
        for (int q = 0; q < 4; ++q)
#pragma unroll
            for (int mt = 0; mt < 2; ++mt) acc[q][mt] = (f32x4){0.f, 0.f, 0.f, 0.f};
        int nt0 = j0 >> 4;
        int kt0 = khalf * 8;
#pragma unroll 4
        for (int kt = kt0; kt < kt0 + 8; ++kt) {
            bf16x8 ah0 = *(const bf16x8*)&Ahi[0][kt][lane][0];
            bf16x8 al0 = *(const bf16x8*)&Alo[0][kt][lane][0];
            bf16x8 ah1 = *(const bf16x8*)&Ahi[1][kt][lane][0];
            bf16x8 al1 = *(const bf16x8*)&Alo[1][kt][lane][0];
#pragma unroll
            for (int q = 0; q < 4; ++q) {
                int ntile = q * 32 + nt0;
                size_t off = ((size_t)(ntile * 16 + kt) * 64 + lane) * 8;
                bf16x8 bh = *(const bf16x8*)(Whi + off);
                bf16x8 bl = *(const bf16x8*)(Wlo + off);
                acc[q][0] = __builtin_amdgcn_mfma_f32_16x16x32_bf16(ah0, bh, acc[q][0], 0, 0, 0);
                acc[q][0] = __builtin_amdgcn_mfma_f32_16x16x32_bf16(ah0, bl, acc[q][0], 0, 0, 0);
                acc[q][0] = __builtin_amdgcn_mfma_f32_16x16x32_bf16(al0, bh, acc[q][0], 0, 0, 0);
                acc[q][1] = __builtin_amdgcn_mfma_f32_16x16x32_bf16(ah1, bh, acc[q][1], 0, 0, 0);
                acc[q][1] = __builtin_amdgcn_mfma_f32_16x16x32_bf16(ah1, bl, acc[q][1], 0, 0, 0);
                acc[q][1] = __builtin_amdgcn_mfma_f32_16x16x32_bf16(al1, bh, acc[q][1], 0, 0, 0);
            }
        }
        __syncthreads();
        float* xch = (float*)&Ahi[0][0][0][0];
        if (khalf == 1) {
#pragma unroll
            for (int q = 0; q < 4; ++q)
#pragma unroll
                for (int mt = 0; mt < 2; ++mt)
                    *(f32x4*)&xch[(((q * 2 + mt) * 128) + js * 64 + lane) * 4] = acc[q][mt];
        }
        __syncthreads();
        if (khalf == 0) {
#pragma unroll
            for (int q = 0; q < 4; ++q)
#pragma unroll
                for (int mt = 0; mt < 2; ++mt) {
                    f32x4 o = *(const f32x4*)&xch[(((q * 2 + mt) * 128) + js * 64 + lane) * 4];
                    acc[q][mt] += o;
                }
            epilogue(j0, acc);
        }
    }
}

// B<=16 levels: fp32 partial GEMM, grid (B, 8, 8), block 256.
__global__ void small_gemm_kernel(
    const int* __restrict__ a_idx, const int* __restrict__ b_idx,
    const float* __restrict__ out, const float* __restrict__ W_hh,
    float* __restrict__ part, int node_base) {
    __shared__ float hs[64];
    int t = threadIdx.x;
    int n = blockIdx.x;
    int node = node_base + n;
    int kbase = blockIdx.z * 64;
    if (t < 16) {
        int child = (kbase < 256) ? a_idx[node] : b_idx[node];
        float4 v = ((const float4*)(out + (size_t)child * 512 + (kbase & 255)))[t];
        ((float4*)hs)[t] = v;
    }
    __syncthreads();
    int r = blockIdx.y * 256 + t;
    const float4* w4 = (const float4*)(W_hh + (size_t)r * 512 + kbase);
    const float4* h4 = (const float4*)hs;
    float acc = 0.f;
#pragma unroll
    for (int k = 0; k < 16; ++k) {
        float4 wv = w4[k];
        float4 hv = h4[k];
        acc += wv.x * hv.x + wv.y * hv.y + wv.z * hv.z + wv.w * hv.w;
    }
    part[((size_t)blockIdx.z * gridDim.x + n) * 2048 + r] = acc;
}

// combine K-partials + LSTM.  grid (B*2), block 256
__global__ void small_combine_kernel(
    const int* __restrict__ a_idx, const int* __restrict__ b_idx,
    const int* __restrict__ types, const float* __restrict__ part,
    const float* __restrict__ proj, float* __restrict__ C256,
    short* __restrict__ Hsplit, float* __restrict__ out, int node_base, int B) {
    int bi = blockIdx.x;
    int n = bi >> 1;
    int j = ((bi & 1) << 8) + threadIdx.x;
    int node = node_base + n;
    float g[4] = {0.f, 0.f, 0.f, 0.f};
    for (int z = 0; z < 8; ++z) {
        const float* p = part + ((size_t)z * B + n) * 2048;
#pragma unroll
        for (int q = 0; q < 4; ++q) g[q] += p[q * 512 + j];
    }
    const float* p = proj + (size_t)types[node] * 2048 + j;
    float gi = g[0] + p[0];
    float gf = g[1] + p[512];
    float gg = g[2] + p[1024];
    float go = g[3] + p[1536];
    int child = (j < 256) ? a_idx[node] : b_idx[node];
    float c = C256[(size_t)child * 256 + (j & 255)];
    float cn = sigf(gf) * c + sigf(gi) * tanhfast(gg);
    float hn = sigf(go) * tanhfast(cn);
    out[(size_t)node * 512 + j] = hn;
    if (j < 256) {
        C256[(size_t)node * 256 + j] = cn;
        short hi = bf_hi(hn);
        Hsplit[(size_t)node * 512 + j] = hi;
        Hsplit[(size_t)node * 512 + 256 + j] = bf_hi(hn - bf_f(hi));
    }
}

extern "C" void kernel_launch(void* const* d_in, const int* in_sizes, int n_in,
                              void* d_out, int out_size, void* d_ws, size_t ws_size,
                              hipStream_t stream) {
    const int* types = (const int*)d_in[0];
    const int* a_idx = (const int*)d_in[1];
    const int* b_idx = (const int*)d_in[2];
    const float* emb = (const float*)d_in[3];
    const float* W_ih = (const float*)d_in[4];
    const float* W_hh = (const float*)d_in[5];
    const float* b_ih = (const float*)d_in[6];
    const float* b_hh = (const float*)d_in[7];
    float* out = (float*)d_out;

    float* ws = (float*)d_ws;
    float* proj = ws;                               // 65536 floats (256 KB)
    float* C256 = ws + 65536;                       // 8388352 floats (32 MB)
    short* Hsplit = (short*)(C256 + 8388352);       // 32767*512 shorts (32 MB)
    short* Whi = Hsplit + 16777216;                 // 2048*512 shorts (2 MB); MUST stay
    short* Wlo = Whi + 1048576;                     // contiguous after Hsplit (WOFF)
    float* part = (float*)(Wlo + 1048576);          // 8*16*2048 floats (1 MB)
    // total ws use ~69.3 MB

    proj_kernel<<<256, 256, 0, stream>>>(emb, W_ih, b_ih, b_hh, proj);
    wpack_kernel<<<512, 256, 0, stream>>>(W_hh, Whi, Wlo);
    leaf_kernel<<<32768, 256, 0, stream>>>(types, proj, out, C256, Hsplit);

    for (int d = 13; d >= 0; --d) {
        int base = (1 << d) - 1;
        int B = 1 << d;
        if (B >= 8192) {
            huge_gemm_lstm_kernel<<<(B / 256) * 8, 512, 0, stream>>>(
                a_idx, b_idx, types, out, proj, C256, Hsplit, base);
        } else if (B >= 1024) {
            int X = B / 128;
            big_gemm_lstm_kernel<<<X * 16, 256, 0, stream>>>(
                a_idx, b_idx, types, out, Whi, proj, C256, Hsplit, base);
        } else if (B >= 32) {
            int bx = B / 32;
            int J = 2;
            while (bx * J < 512 && J < 16) J <<= 1;
            gemm_lstm_kernel<<<dim3(bx, J), 256, 0, stream>>>(
                a_idx, b_idx, types, out, Whi, Wlo, proj, C256, Hsplit, base, 512 / J);
        } else {
            small_gemm_kernel<<<dim3(B, 8, 8), 256, 0, stream>>>(
                a_idx, b_idx, out, W_hh, part, base);
            small_combine_kernel<<<B * 2, 256, 0, stream>>>(
                a_idx, b_idx, types, part, proj, C256, Hsplit, out, base, B);
        }
    }
}

// Round 8
// 410.322 us; speedup vs baseline: 1.2675x; 1.0135x over previous
//
#include <hip/hip_runtime.h>
#include <hip/hip_bf16.h>

// Tree-LSTM, depth-15 complete binary tree. N=32767, state 2H=512, gates 2048.
// R11: big levels (B>=1024, d13..d10) use big_v2 = R5b geometry (128x128 tile,
// 64KB LDS, 2 blocks/CU = 8 waves/CU cross-block overlap) + R10's reformed
// contiguous A-staging (8 rows x 128B per inst, 16 lines, XOR-swizzled source)
// + counted-vmcnt 2-barrier schedule (no mid-loop drain).
// d9..d5: gemm_lstm; d4..d0: small_gemm+small_combine. (huge kernel retired:
// its 77.5us at d13 is the number to beat.)

#define NNODES 32767

typedef __attribute__((ext_vector_type(8))) short bf16x8;
typedef __attribute__((ext_vector_type(4))) float f32x4;

typedef const __attribute__((address_space(1))) void* gptr_t;
typedef __attribute__((address_space(3))) void* lptr_t;

__device__ __forceinline__ float sigf(float x) { return 1.0f / (1.0f + __expf(-x)); }
__device__ __forceinline__ float tanhfast(float x) { return 2.0f / (1.0f + __expf(-2.0f * x)) - 1.0f; }

__device__ __forceinline__ short bf_hi(float x) {
    __hip_bfloat16 h = __float2bfloat16(x);
    return __builtin_bit_cast(short, h);
}
__device__ __forceinline__ float bf_f(short s) {
    __hip_bfloat16 h = __builtin_bit_cast(__hip_bfloat16, s);
    return __bfloat162float(h);
}
__device__ __forceinline__ void split8(const float* src, short* hi, short* lo) {
#pragma unroll
    for (int j = 0; j < 8; ++j) {
        float x = src[j];
        short h = bf_hi(x);
        hi[j] = h;
        lo[j] = bf_hi(x - bf_f(h));
    }
}

// proj[v][r] = dot(emb[v], W_ih[r]) + b_ih[r] + b_hh[r];  grid 256, block 256
__global__ void proj_kernel(const float* __restrict__ emb, const float* __restrict__ W_ih,
                            const float* __restrict__ b_ih, const float* __restrict__ b_hh,
                            float* __restrict__ proj) {
    __shared__ float e[256];
    int v = blockIdx.x >> 3;
    int rc = blockIdx.x & 7;
    int t = threadIdx.x;
    e[t] = emb[v * 256 + t];
    __syncthreads();
    int r = rc * 256 + t;
    const float4* w4 = (const float4*)(W_ih + (size_t)r * 256);
    const float4* e4 = (const float4*)e;
    float acc = 0.f;
#pragma unroll 8
    for (int k = 0; k < 64; ++k) {
        float4 w = w4[k];
        float4 h = e4[k];
        acc += w.x * h.x + w.y * h.y + w.z * h.z + w.w * h.w;
    }
    proj[v * 2048 + r] = acc + b_ih[r] + b_hh[r];
}

// W_hh [2048][512] fp32 -> MFMA B-fragment bf16 hi/lo tables.  grid 512, block 256
__global__ void wpack_kernel(const float* __restrict__ W_hh,
                             short* __restrict__ Whi, short* __restrict__ Wlo) {
    int t = blockIdx.x * 256 + threadIdx.x;
    int lane = t & 63;
    int kt = (t >> 6) & 15;
    int ntile = t >> 10;
    int n = ntile * 16 + (lane & 15);
    int k0 = kt * 32 + (lane >> 4) * 8;
    const float* src = W_hh + (size_t)n * 512 + k0;
    short hi[8], lo[8];
    split8(src, hi, lo);
    *(bf16x8*)(Whi + (size_t)t * 8) = *(bf16x8*)hi;
    *(bf16x8*)(Wlo + (size_t)t * 8) = *(bf16x8*)lo;
}

// leaves: gates = proj[type].  grid 32768, block 256
__global__ void leaf_kernel(const int* __restrict__ types, const float* __restrict__ proj,
                            float* __restrict__ out, float* __restrict__ C256,
                            short* __restrict__ Hsplit) {
    int bi = blockIdx.x;
    int node = 16383 + (bi >> 1);
    int j = ((bi & 1) << 8) + threadIdx.x;
    int tt = types[node];
    const float* p = proj + (size_t)tt * 2048;
    float gi = p[j];
    float gg = p[1024 + j];
    float go = p[1536 + j];
    float cn = sigf(gi) * tanhfast(gg);
    float hn = sigf(go) * tanhfast(cn);
    out[(size_t)node * 512 + j] = hn;
    if ((bi & 1) == 0) {
        C256[(size_t)node * 256 + j] = cn;
        short hi = bf_hi(hn);
        Hsplit[(size_t)node * 512 + j] = hi;
        Hsplit[(size_t)node * 512 + 256 + j] = bf_hi(hn - bf_f(hi));
    }
}

// ---------------------------------------------------------------------------
// Big levels (B >= 1024): big_v2. 256 thr / 4 waves (2M x 2N), tile 128 nodes
// x 128 gate-rows (4 gates x 32 j), BK=32. 2 x 32KB LDS dbuf -> 2 blocks/CU.
// A chunks (0..15): 8 rows x 128B contiguous (hi64+lo64), source XOR-swizzled
//   j = slot ^ row; read slot = r*8 + (piece ^ r).  16 lines/inst.
// W chunks (16..31): linear packed fragments, rel. Hsplit via WOFF.
// Counted-vmcnt 2-barrier pipeline: never drains mid-loop.
// ---------------------------------------------------------------------------
__global__ __launch_bounds__(256) void big_gemm_lstm_kernel(
    const int* __restrict__ a_idx, const int* __restrict__ b_idx,
    const int* __restrict__ types, float* __restrict__ out,
    const float* __restrict__ proj, float* __restrict__ C256,
    short* __restrict__ Hsplit, int node_base) {
    __shared__ __align__(16) short lds[2][16384];  // 64 KB: 2 x 32 chunks x 512
    __shared__ int sA[128], sB[128], sT[128];

    const unsigned WOFF = 16777216u;  // Whi - Hsplit in shorts (ws layout)

    int t = threadIdx.x;
    int lin = blockIdx.x;
    int x = lin >> 4;
    int y = (lin & 7) * 2 + ((lin >> 3) & 1);  // XCD swizzle, bijective for X*16
    int node0 = node_base + x * 128;
    int j0 = y * 32;

    if (t < 128) {
        sA[t] = a_idx[node0 + t];
        sB[t] = b_idx[node0 + t];
        sT[t] = types[node0 + t];
    }
    __syncthreads();

    int w = t >> 6, lane = t & 63;
    int wm = w >> 1, wn = w & 1;

    // Staging bases (short offsets rel. Hsplit). Chunk c = w*8+i.
    // Waves 0,1: A chunks 0..15: lane l -> row ca*8 + (l>>3), piece
    //   j = (l&7) ^ (l>>3); src = child*512 + (j>>2)*256 + (j&3)*8 (+kt*32).
    // Waves 2,3: W chunks 16..31 (cc = c-16): linear fragments, +kt*512.
    unsigned b0[8], b1[8], sk;
    if (w < 2) {
        sk = 32u;
#pragma unroll
        for (int i = 0; i < 8; ++i) {
            int ca = w * 8 + i;
            int rl = lane >> 3;
            int r_loc = ca * 8 + rl;
            int j = (lane & 7) ^ rl;
            unsigned ks = (unsigned)(j >> 2) * 256u + (unsigned)(j & 3) * 8u;
            b0[i] = (unsigned)sA[r_loc] * 512u + ks;
            b1[i] = (unsigned)sB[r_loc] * 512u + ks;
        }
    } else {
        sk = 512u;
#pragma unroll
        for (int i = 0; i < 8; ++i) {
            int cc = (w - 2) * 8 + i;
            int nt = cc >> 1, part = cc & 1;
            int q = nt >> 1, sub = nt & 1;
            unsigned ntg = (unsigned)(q * 32 + y * 2 + sub);
            b0[i] = WOFF + ntg * 8192u + (unsigned)part * 1048576u + (unsigned)lane * 8u;
            b1[i] = b0[i] + 4096u;
        }
    }

    f32x4 acc[4][4];
#pragma unroll
    for (int i = 0; i < 4; ++i)
#pragma unroll
        for (int q = 0; q < 4; ++q) acc[i][q] = (f32x4){0.f, 0.f, 0.f, 0.f};

    auto stage = [&](int kt, int buf) {
#pragma unroll
        for (int i = 0; i < 8; ++i) {
            unsigned off = ((kt < 8) ? b0[i] : b1[i]) + (unsigned)(kt & 7) * sk;
            const short* gsrc = Hsplit + off;
            short* ldst = &lds[buf][(w * 8 + i) * 512];
            __builtin_amdgcn_global_load_lds((gptr_t)gsrc, (lptr_t)ldst, 16, 0, 0);
        }
    };

    auto compute = [&](int buf) {
        const short* L = lds[buf];
        int s = lane >> 4;  // k-sub 0..3
        bf16x8 ah[4], al[4];
#pragma unroll
        for (int i = 0; i < 4; ++i) {
            int m_loc = (wm * 4 + i) * 16 + (lane & 15);
            int ch = m_loc >> 3;
            int r = m_loc & 7;
            const short* base = L + ch * 512 + r * 64;
            ah[i] = *(const bf16x8*)&base[(s ^ r) * 8];
            al[i] = *(const bf16x8*)&base[((4 + s) ^ r) * 8];
        }
        __builtin_amdgcn_s_setprio(1);
#pragma unroll
        for (int q = 0; q < 4; ++q) {
            int nt = q * 2 + wn;
            bf16x8 bh = *(const bf16x8*)&L[(16 + nt * 2) * 512 + lane * 8];
            bf16x8 bl = *(const bf16x8*)&L[(17 + nt * 2) * 512 + lane * 8];
#pragma unroll
            for (int i = 0; i < 4; ++i) {
                acc[i][q] = __builtin_amdgcn_mfma_f32_16x16x32_bf16(ah[i], bh, acc[i][q], 0, 0, 0);
                acc[i][q] = __builtin_amdgcn_mfma_f32_16x16x32_bf16(ah[i], bl, acc[i][q], 0, 0, 0);
                acc[i][q] = __builtin_amdgcn_mfma_f32_16x16x32_bf16(al[i], bh, acc[i][q], 0, 0, 0);
            }
        }
        __builtin_amdgcn_s_setprio(0);
    };

    stage(0, 0);
    int cur = 0;
#pragma unroll 1
    for (int kt = 0; kt < 16; ++kt) {
        // barrier A: all waves done reading lds[cur^1] (compute(kt-1))
        __builtin_amdgcn_s_barrier();
        if (kt < 15) stage(kt + 1, cur ^ 1);
        // my stage(kt) landed; stage(kt+1)'s 8 loads stay in flight
        if (kt < 15) {
            asm volatile("s_waitcnt vmcnt(8)" ::: "memory");
        } else {
            asm volatile("s_waitcnt vmcnt(0)" ::: "memory");
        }
        // barrier B: ALL waves' stage(kt) landed
        __builtin_amdgcn_s_barrier();
        compute(cur);
        cur ^= 1;
    }

    int j = j0 + wn * 16 + (lane & 15);
    bool fh = (j < 256);
    int jc = j & 255;
#pragma unroll
    for (int i = 0; i < 4; ++i) {
        int mrow = wm * 64 + i * 16 + (lane >> 4) * 4;
#pragma unroll
        for (int r = 0; r < 4; ++r) {
            int m_loc = mrow + r;
            int node = node0 + m_loc;
            const float* p = proj + (size_t)sT[m_loc] * 2048 + j;
            float gi = acc[i][0][r] + p[0];
            float gf = acc[i][1][r] + p[512];
            float gg = acc[i][2][r] + p[1024];
            float go = acc[i][3][r] + p[1536];
            int child = fh ? sA[m_loc] : sB[m_loc];
            float c = C256[(size_t)child * 256 + jc];
            float cn = sigf(gf) * c + sigf(gi) * tanhfast(gg);
            float hn = sigf(go) * tanhfast(cn);
            out[(size_t)node * 512 + j] = hn;
            if (fh) {
                C256[(size_t)node * 256 + j] = cn;
                short hi = bf_hi(hn);
                Hsplit[(size_t)node * 512 + j] = hi;
                Hsplit[(size_t)node * 512 + 256 + j] = bf_hi(hn - bf_f(hi));
            }
        }
    }
}

// Fused MFMA GEMM + LSTM (mid levels 32..512).  32 nodes/block, grid (B/32, J).
__global__ __launch_bounds__(256) void gemm_lstm_kernel(
    const int* __restrict__ a_idx, const int* __restrict__ b_idx,
    const int* __restrict__ types, float* __restrict__ out,
    const short* __restrict__ Whi, const short* __restrict__ Wlo,
    const float* __restrict__ proj, float* __restrict__ C256,
    short* __restrict__ Hsplit, int node_base, int Jc) {
    __shared__ short Ahi[2][16][64][8];   // 32 KB
    __shared__ short Alo[2][16][64][8];   // 32 KB
    __shared__ int sA[32], sB[32], sT[32];
    int t = threadIdx.x;
    int node0 = node_base + blockIdx.x * 32;
    if (t < 32) {
        sA[t] = a_idx[node0 + t];
        sB[t] = b_idx[node0 + t];
        sT[t] = types[node0 + t];
    }
    __syncthreads();

#pragma unroll
    for (int it = 0; it < 8; ++it) {
        int c = it * 256 + t;
        int mt = c >> 10;
        int kt = (c >> 6) & 15;
        int lane = c & 63;
        int m_loc = mt * 16 + (lane & 15);
        int k0 = kt * 32 + (lane >> 4) * 8;
        int child = (k0 < 256) ? sA[m_loc] : sB[m_loc];
        const short* src = Hsplit + (size_t)child * 512 + (k0 & 255);
        *(bf16x8*)&Ahi[mt][kt][lane][0] = *(const bf16x8*)src;
        *(bf16x8*)&Alo[mt][kt][lane][0] = *(const bf16x8*)(src + 256);
    }
    __syncthreads();

    int w = t >> 6;
    int lane = t & 63;
    int jsteps = Jc >> 4;
    int jbase = blockIdx.y * Jc;

    auto epilogue = [&](int j0, f32x4 (&acc)[4][2]) {
        int j = j0 + (lane & 15);
        int jc = j & 255;
        bool fh = (j < 256);
#pragma unroll
        for (int mt = 0; mt < 2; ++mt) {
            int mrow = mt * 16 + (lane >> 4) * 4;
#pragma unroll
            for (int r = 0; r < 4; ++r) {
                int m_loc = mrow + r;
                int node = node0 + m_loc;
                const float* p = proj + (size_t)sT[m_loc] * 2048 + j;
                float gi = acc[0][mt][r] + p[0];
                float gf = acc[1][mt][r] + p[512];
                float gg = acc[2][mt][r] + p[1024];
                float go = acc[3][mt][r] + p[1536];
                int child = fh ? sA[m_loc] : sB[m_loc];
                float c = C256[(size_t)child * 256 + jc];
                float cn = sigf(gf) * c + sigf(gi) * tanhfast(gg);
                float hn = sigf(go) * tanhfast(cn);
                out[(size_t)node * 512 + j] = hn;
                if (fh) {
                    C256[(size_t)node * 256 + j] = cn;
                    short hi = bf_hi(hn);
                    Hsplit[(size_t)node * 512 + j] = hi;
                    Hsplit[(size_t)node * 512 + 256 + j] = bf_hi(hn - bf_f(hi));
                }
            }
        }
    };

    if (jsteps >= 4) {
        for (int js = w; js < jsteps; js += 4) {
            int j0 = jbase + js * 16;
            f32x4 acc[4][2];
#pragma unroll
            for (int q = 0; q < 4; ++q)
#pragma unroll
                for (int mt = 0; mt < 2; ++mt) acc[q][mt] = (f32x4){0.f, 0.f, 0.f, 0.f};
            int nt0 = j0 >> 4;
#pragma unroll 4
            for (int kt = 0; kt < 16; ++kt) {
                bf16x8 ah0 = *(const bf16x8*)&Ahi[0][kt][lane][0];
                bf16x8 al0 = *(const bf16x8*)&Alo[0][kt][lane][0];
                bf16x8 ah1 = *(const bf16x8*)&Ahi[1][kt][lane][0];
                bf16x8 al1 = *(const bf16x8*)&Alo[1][kt][lane][0];
#pragma unroll
                for (int q = 0; q < 4; ++q) {
                    int ntile = q * 32 + nt0;
                    size_t off = ((size_t)(ntile * 16 + kt) * 64 + lane) * 8;
                    bf16x8 bh = *(const bf16x8*)(Whi + off);
                    bf16x8 bl = *(const bf16x8*)(Wlo + off);
                    acc[q][0] = __builtin_amdgcn_mfma_f32_16x16x32_bf16(ah0, bh, acc[q][0], 0, 0, 0);
                    acc[q][0] = __builtin_amdgcn_mfma_f32_16x16x32_bf16(ah0, bl, acc[q][0], 0, 0, 0);
                    acc[q][0] = __builtin_amdgcn_mfma_f32_16x16x32_bf16(al0, bh, acc[q][0], 0, 0, 0);
                    acc[q][1] = __builtin_amdgcn_mfma_f32_16x16x32_bf16(ah1, bh, acc[q][1], 0, 0, 0);
                    acc[q][1] = __builtin_amdgcn_mfma_f32_16x16x32_bf16(ah1, bl, acc[q][1], 0, 0, 0);
                    acc[q][1] = __builtin_amdgcn_mfma_f32_16x16x32_bf16(al1, bh, acc[q][1], 0, 0, 0);
                }
            }
            epilogue(j0, acc);
        }
    } else {
        int js = w & 1;
        int khalf = w >> 1;
        int j0 = jbase + js * 16;
        f32x4 acc[4][2];
#pragma unroll
        for (int q = 0; q < 4; ++q)
#pragma unroll
            for (int mt = 0; mt < 2; ++mt) acc[q][mt] = (f32x4){0.f, 0.f, 0.f, 0.f};
        int nt0 = j0 >> 4;
        int kt0 = khalf * 8;
#pragma unroll 4
        for (int kt = kt0; kt < kt0 + 8; ++kt) {
            bf16x8 ah0 = *(const bf16x8*)&Ahi[0][kt][lane][0];
            bf16x8 al0 = *(const bf16x8*)&Alo[0][kt][lane][0];
            bf16x8 ah1 = *(const bf16x8*)&Ahi[1][kt][lane][0];
            bf16x8 al1 = *(const bf16x8*)&Alo[1][kt][lane][0];
#pragma unroll
            for (int q = 0; q < 4; ++q) {
                int ntile = q * 32 + nt0;
                size_t off = ((size_t)(ntile * 16 + kt) * 64 + lane) * 8;
                bf16x8 bh = *(const bf16x8*)(Whi + off);
                bf16x8 bl = *(const bf16x8*)(Wlo + off);
                acc[q][0] = __builtin_amdgcn_mfma_f32_16x16x32_bf16(ah0, bh, acc[q][0], 0, 0, 0);
                acc[q][0] = __builtin_amdgcn_mfma_f32_16x16x32_bf16(ah0, bl, acc[q][0], 0, 0, 0);
                acc[q][0] = __builtin_amdgcn_mfma_f32_16x16x32_bf16(al0, bh, acc[q][0], 0, 0, 0);
                acc[q][1] = __builtin_amdgcn_mfma_f32_16x16x32_bf16(ah1, bh, acc[q][1], 0, 0, 0);
                acc[q][1] = __builtin_amdgcn_mfma_f32_16x16x32_bf16(ah1, bl, acc[q][1], 0, 0, 0);
                acc[q][1] = __builtin_amdgcn_mfma_f32_16x16x32_bf16(al1, bh, acc[q][1], 0, 0, 0);
            }
        }
        __syncthreads();
        float* xch = (float*)&Ahi[0][0][0][0];
        if (khalf == 1) {
#pragma unroll
            for (int q = 0; q < 4; ++q)
#pragma unroll
                for (int mt = 0; mt < 2; ++mt)
                    *(f32x4*)&xch[(((q * 2 + mt) * 128) + js * 64 + lane) * 4] = acc[q][mt];
        }
        __syncthreads();
        if (khalf == 0) {
#pragma unroll
            for (int q = 0; q < 4; ++q)
#pragma unroll
                for (int mt = 0; mt < 2; ++mt) {
                    f32x4 o = *(const f32x4*)&xch[(((q * 2 + mt) * 128) + js * 64 + lane) * 4];
                    acc[q][mt] += o;
                }
            epilogue(j0, acc);
        }
    }
}

// B<=16 levels: fp32 partial GEMM, grid (B, 8, 8), block 256.
__global__ void small_gemm_kernel(
    const int* __restrict__ a_idx, const int* __restrict__ b_idx,
    const float* __restrict__ out, const float* __restrict__ W_hh,
    float* __restrict__ part, int node_base) {
    __shared__ float hs[64];
    int t = threadIdx.x;
    int n = blockIdx.x;
    int node = node_base + n;
    int kbase = blockIdx.z * 64;
    if (t < 16) {
        int child = (kbase < 256) ? a_idx[node] : b_idx[node];
        float4 v = ((const float4*)(out + (size_t)child * 512 + (kbase & 255)))[t];
        ((float4*)hs)[t] = v;
    }
    __syncthreads();
    int r = blockIdx.y * 256 + t;
    const float4* w4 = (const float4*)(W_hh + (size_t)r * 512 + kbase);
    const float4* h4 = (const float4*)hs;
    float acc = 0.f;
#pragma unroll
    for (int k = 0; k < 16; ++k) {
        float4 wv = w4[k];
        float4 hv = h4[k];
        acc += wv.x * hv.x + wv.y * hv.y + wv.z * hv.z + wv.w * hv.w;
    }
    part[((size_t)blockIdx.z * gridDim.x + n) * 2048 + r] = acc;
}

// combine K-partials + LSTM.  grid (B*2), block 256
__global__ void small_combine_kernel(
    const int* __restrict__ a_idx, const int* __restrict__ b_idx,
    const int* __restrict__ types, const float* __restrict__ part,
    const float* __restrict__ proj, float* __restrict__ C256,
    short* __restrict__ Hsplit, float* __restrict__ out, int node_base, int B) {
    int bi = blockIdx.x;
    int n = bi >> 1;
    int j = ((bi & 1) << 8) + threadIdx.x;
    int node = node_base + n;
    float g[4] = {0.f, 0.f, 0.f, 0.f};
    for (int z = 0; z < 8; ++z) {
        const float* p = part + ((size_t)z * B + n) * 2048;
#pragma unroll
        for (int q = 0; q < 4; ++q) g[q] += p[q * 512 + j];
    }
    const float* p = proj + (size_t)types[node] * 2048 + j;
    float gi = g[0] + p[0];
    float gf = g[1] + p[512];
    float gg = g[2] + p[1024];
    float go = g[3] + p[1536];
    int child = (j < 256) ? a_idx[node] : b_idx[node];
    float c = C256[(size_t)child * 256 + (j & 255)];
    float cn = sigf(gf) * c + sigf(gi) * tanhfast(gg);
    float hn = sigf(go) * tanhfast(cn);
    out[(size_t)node * 512 + j] = hn;
    if (j < 256) {
        C256[(size_t)node * 256 + j] = cn;
        short hi = bf_hi(hn);
        Hsplit[(size_t)node * 512 + j] = hi;
        Hsplit[(size_t)node * 512 + 256 + j] = bf_hi(hn - bf_f(hi));
    }
}

extern "C" void kernel_launch(void* const* d_in, const int* in_sizes, int n_in,
                              void* d_out, int out_size, void* d_ws, size_t ws_size,
                              hipStream_t stream) {
    const int* types = (const int*)d_in[0];
    const int* a_idx = (const int*)d_in[1];
    const int* b_idx = (const int*)d_in[2];
    const float* emb = (const float*)d_in[3];
    const float* W_ih = (const float*)d_in[4];
    const float* W_hh = (const float*)d_in[5];
    const float* b_ih = (const float*)d_in[6];
    const float* b_hh = (const float*)d_in[7];
    float* out = (float*)d_out;

    float* ws = (float*)d_ws;
    float* proj = ws;                               // 65536 floats (256 KB)
    float* C256 = ws + 65536;                       // 8388352 floats (32 MB)
    short* Hsplit = (short*)(C256 + 8388352);       // 32767*512 shorts (32 MB)
    short* Whi = Hsplit + 16777216;                 // 2048*512 shorts (2 MB); MUST stay
    short* Wlo = Whi + 1048576;                     // contiguous after Hsplit (WOFF)
    float* part = (float*)(Wlo + 1048576);          // 8*16*2048 floats (1 MB)
    // total ws use ~69.3 MB

    proj_kernel<<<256, 256, 0, stream>>>(emb, W_ih, b_ih, b_hh, proj);
    wpack_kernel<<<512, 256, 0, stream>>>(W_hh, Whi, Wlo);
    leaf_kernel<<<32768, 256, 0, stream>>>(types, proj, out, C256, Hsplit);

    for (int d = 13; d >= 0; --d) {
        int base = (1 << d) - 1;
        int B = 1 << d;
        if (B >= 1024) {
            int X = B / 128;
            big_gemm_lstm_kernel<<<X * 16, 256, 0, stream>>>(
                a_idx, b_idx, types, out, proj, C256, Hsplit, base);
        } else if (B >= 32) {
            int bx = B / 32;
            int J = 2;
            while (bx * J < 512 && J < 16) J <<= 1;
            gemm_lstm_kernel<<<dim3(bx, J), 256, 0, stream>>>(
                a_idx, b_idx, types, out, Whi, Wlo, proj, C256, Hsplit, base, 512 / J);
        } else {
            small_gemm_kernel<<<dim3(B, 8, 8), 256, 0, stream>>>(
                a_idx, b_idx, out, W_hh, part, base);
            small_combine_kernel<<<B * 2, 256, 0, stream>>>(
                a_idx, b_idx, types, part, proj, C256, Hsplit, out, base, B);
        }
    }
}

// Round 10
// 401.953 us; speedup vs baseline: 1.2939x; 1.0208x over previous
//
#include <hip/hip_runtime.h>
#include <hip/hip_bf16.h>

// Tree-LSTM, depth-15 complete binary tree. N=32767, state 2H=512, gates 2048.
// R12b = resubmit of R12 (prior bench failed at infra level, no counters).
// R12 = R11 (best measured, 410us) with ONE change: small levels (B<=16) use
// smallv2_gemm_kernel -- W read ONCE per level from the packed bf16 hi/lo
// tables (4MB) instead of once PER NODE from fp32 W_hh (B x 16MB):
//  - grid (8 y x 8 z), 256 thr; thread owns row r = y*256+t, k in [z*64,+64)
//  - W row-slice reconstructed (hi+lo) into 64 VGPRs; h for all B nodes in LDS
//  - part layout unchanged -> small_combine_kernel unchanged.
// Big levels (>=1024): R11 big_v2 (reformed A-staging + counted-vmcnt).
// Mid (32..512): gemm_lstm.

#define NNODES 32767

typedef __attribute__((ext_vector_type(8))) short bf16x8;
typedef __attribute__((ext_vector_type(4))) float f32x4;

typedef const __attribute__((address_space(1))) void* gptr_t;
typedef __attribute__((address_space(3))) void* lptr_t;

__device__ __forceinline__ float sigf(float x) { return 1.0f / (1.0f + __expf(-x)); }
__device__ __forceinline__ float tanhfast(float x) { return 2.0f / (1.0f + __expf(-2.0f * x)) - 1.0f; }

__device__ __forceinline__ short bf_hi(float x) {
    __hip_bfloat16 h = __float2bfloat16(x);
    return __builtin_bit_cast(short, h);
}
__device__ __forceinline__ float bf_f(short s) {
    __hip_bfloat16 h = __builtin_bit_cast(__hip_bfloat16, s);
    return __bfloat162float(h);
}
__device__ __forceinline__ void split8(const float* src, short* hi, short* lo) {
#pragma unroll
    for (int j = 0; j < 8; ++j) {
        float x = src[j];
        short h = bf_hi(x);
        hi[j] = h;
        lo[j] = bf_hi(x - bf_f(h));
    }
}

// proj[v][r] = dot(emb[v], W_ih[r]) + b_ih[r] + b_hh[r];  grid 256, block 256
__global__ void proj_kernel(const float* __restrict__ emb, const float* __restrict__ W_ih,
                            const float* __restrict__ b_ih, const float* __restrict__ b_hh,
                            float* __restrict__ proj) {
    __shared__ float e[256];
    int v = blockIdx.x >> 3;
    int rc = blockIdx.x & 7;
    int t = threadIdx.x;
    e[t] = emb[v * 256 + t];
    __syncthreads();
    int r = rc * 256 + t;
    const float4* w4 = (const float4*)(W_ih + (size_t)r * 256);
    const float4* e4 = (const float4*)e;
    float acc = 0.f;
#pragma unroll 8
    for (int k = 0; k < 64; ++k) {
        float4 w = w4[k];
        float4 h = e4[k];
        acc += w.x * h.x + w.y * h.y + w.z * h.z + w.w * h.w;
    }
    proj[v * 2048 + r] = acc + b_ih[r] + b_hh[r];
}

// W_hh [2048][512] fp32 -> MFMA B-fragment bf16 hi/lo tables.  grid 512, block 256
__global__ void wpack_kernel(const float* __restrict__ W_hh,
                             short* __restrict__ Whi, short* __restrict__ Wlo) {
    int t = blockIdx.x * 256 + threadIdx.x;
    int lane = t & 63;
    int kt = (t >> 6) & 15;
    int ntile = t >> 10;
    int n = ntile * 16 + (lane & 15);
    int k0 = kt * 32 + (lane >> 4) * 8;
    const float* src = W_hh + (size_t)n * 512 + k0;
    short hi[8], lo[8];
    split8(src, hi, lo);
    *(bf16x8*)(Whi + (size_t)t * 8) = *(bf16x8*)hi;
    *(bf16x8*)(Wlo + (size_t)t * 8) = *(bf16x8*)lo;
}

// leaves: gates = proj[type].  grid 32768, block 256
__global__ void leaf_kernel(const int* __restrict__ types, const float* __restrict__ proj,
                            float* __restrict__ out, float* __restrict__ C256,
                            short* __restrict__ Hsplit) {
    int bi = blockIdx.x;
    int node = 16383 + (bi >> 1);
    int j = ((bi & 1) << 8) + threadIdx.x;
    int tt = types[node];
    const float* p = proj + (size_t)tt * 2048;
    float gi = p[j];
    float gg = p[1024 + j];
    float go = p[1536 + j];
    float cn = sigf(gi) * tanhfast(gg);
    float hn = sigf(go) * tanhfast(cn);
    out[(size_t)node * 512 + j] = hn;
    if ((bi & 1) == 0) {
        C256[(size_t)node * 256 + j] = cn;
        short hi = bf_hi(hn);
        Hsplit[(size_t)node * 512 + j] = hi;
        Hsplit[(size_t)node * 512 + 256 + j] = bf_hi(hn - bf_f(hi));
    }
}

// ---------------------------------------------------------------------------
// Big levels (B >= 1024): big_v2 (R11, unchanged). 256 thr / 4 waves, tile
// 128 x 128, BK=32, 2 x 32KB LDS dbuf (2 blocks/CU), reformed contiguous
// A-staging (XOR-swizzled source), counted-vmcnt 2-barrier pipeline.
// ---------------------------------------------------------------------------
__global__ __launch_bounds__(256) void big_gemm_lstm_kernel(
    const int* __restrict__ a_idx, const int* __restrict__ b_idx,
    const int* __restrict__ types, float* __restrict__ out,
    const float* __restrict__ proj, float* __restrict__ C256,
    short* __restrict__ Hsplit, int node_base) {
    __shared__ __align__(16) short lds[2][16384];  // 64 KB: 2 x 32 chunks x 512
    __shared__ int sA[128], sB[128], sT[128];

    const unsigned WOFF = 16777216u;  // Whi - Hsplit in shorts (ws layout)

    int t = threadIdx.x;
    int lin = blockIdx.x;
    int x = lin >> 4;
    int y = (lin & 7) * 2 + ((lin >> 3) & 1);  // XCD swizzle, bijective for X*16
    int node0 = node_base + x * 128;
    int j0 = y * 32;

    if (t < 128) {
        sA[t] = a_idx[node0 + t];
        sB[t] = b_idx[node0 + t];
        sT[t] = types[node0 + t];
    }
    __syncthreads();

    int w = t >> 6, lane = t & 63;
    int wm = w >> 1, wn = w & 1;

    unsigned b0[8], b1[8], sk;
    if (w < 2) {
        sk = 32u;
#pragma unroll
        for (int i = 0; i < 8; ++i) {
            int ca = w * 8 + i;
            int rl = lane >> 3;
            int r_loc = ca * 8 + rl;
            int j = (lane & 7) ^ rl;
            unsigned ks = (unsigned)(j >> 2) * 256u + (unsigned)(j & 3) * 8u;
            b0[i] = (unsigned)sA[r_loc] * 512u + ks;
            b1[i] = (unsigned)sB[r_loc] * 512u + ks;
        }
    } else {
        sk = 512u;
#pragma unroll
        for (int i = 0; i < 8; ++i) {
            int cc = (w - 2) * 8 + i;
            int nt = cc >> 1, part = cc & 1;
            int q = nt >> 1, sub = nt & 1;
            unsigned ntg = (unsigned)(q * 32 + y * 2 + sub);
            b0[i] = WOFF + ntg * 8192u + (unsigned)part * 1048576u + (unsigned)lane * 8u;
            b1[i] = b0[i] + 4096u;
        }
    }

    f32x4 acc[4][4];
#pragma unroll
    for (int i = 0; i < 4; ++i)
#pragma unroll
        for (int q = 0; q < 4; ++q) acc[i][q] = (f32x4){0.f, 0.f, 0.f, 0.f};

    auto stage = [&](int kt, int buf) {
#pragma unroll
        for (int i = 0; i < 8; ++i) {
            unsigned off = ((kt < 8) ? b0[i] : b1[i]) + (unsigned)(kt & 7) * sk;
            const short* gsrc = Hsplit + off;
            short* ldst = &lds[buf][(w * 8 + i) * 512];
            __builtin_amdgcn_global_load_lds((gptr_t)gsrc, (lptr_t)ldst, 16, 0, 0);
        }
    };

    auto compute = [&](int buf) {
        const short* L = lds[buf];
        int s = lane >> 4;
        bf16x8 ah[4], al[4];
#pragma unroll
        for (int i = 0; i < 4; ++i) {
            int m_loc = (wm * 4 + i) * 16 + (lane & 15);
            int ch = m_loc >> 3;
            int r = m_loc & 7;
            const short* base = L + ch * 512 + r * 64;
            ah[i] = *(const bf16x8*)&base[(s ^ r) * 8];
            al[i] = *(const bf16x8*)&base[((4 + s) ^ r) * 8];
        }
        __builtin_amdgcn_s_setprio(1);
#pragma unroll
        for (int q = 0; q < 4; ++q) {
            int nt = q * 2 + wn;
            bf16x8 bh = *(const bf16x8*)&L[(16 + nt * 2) * 512 + lane * 8];
            bf16x8 bl = *(const bf16x8*)&L[(17 + nt * 2) * 512 + lane * 8];
#pragma unroll
            for (int i = 0; i < 4; ++i) {
                acc[i][q] = __builtin_amdgcn_mfma_f32_16x16x32_bf16(ah[i], bh, acc[i][q], 0, 0, 0);
                acc[i][q] = __builtin_amdgcn_mfma_f32_16x16x32_bf16(ah[i], bl, acc[i][q], 0, 0, 0);
                acc[i][q] = __builtin_amdgcn_mfma_f32_16x16x32_bf16(al[i], bh, acc[i][q], 0, 0, 0);
            }
        }
        __builtin_amdgcn_s_setprio(0);
    };

    stage(0, 0);
    int cur = 0;
#pragma unroll 1
    for (int kt = 0; kt < 16; ++kt) {
        __builtin_amdgcn_s_barrier();
        if (kt < 15) stage(kt + 1, cur ^ 1);
        if (kt < 15) {
            asm volatile("s_waitcnt vmcnt(8)" ::: "memory");
        } else {
            asm volatile("s_waitcnt vmcnt(0)" ::: "memory");
        }
        __builtin_amdgcn_s_barrier();
        compute(cur);
        cur ^= 1;
    }

    int j = j0 + wn * 16 + (lane & 15);
    bool fh = (j < 256);
    int jc = j & 255;
#pragma unroll
    for (int i = 0; i < 4; ++i) {
        int mrow = wm * 64 + i * 16 + (lane >> 4) * 4;
#pragma unroll
        for (int r = 0; r < 4; ++r) {
            int m_loc = mrow + r;
            int node = node0 + m_loc;
            const float* p = proj + (size_t)sT[m_loc] * 2048 + j;
            float gi = acc[i][0][r] + p[0];
            float gf = acc[i][1][r] + p[512];
            float gg = acc[i][2][r] + p[1024];
            float go = acc[i][3][r] + p[1536];
            int child = fh ? sA[m_loc] : sB[m_loc];
            float c = C256[(size_t)child * 256 + jc];
            float cn = sigf(gf) * c + sigf(gi) * tanhfast(gg);
            float hn = sigf(go) * tanhfast(cn);
            out[(size_t)node * 512 + j] = hn;
            if (fh) {
                C256[(size_t)node * 256 + j] = cn;
                short hi = bf_hi(hn);
                Hsplit[(size_t)node * 512 + j] = hi;
                Hsplit[(size_t)node * 512 + 256 + j] = bf_hi(hn - bf_f(hi));
            }
        }
    }
}

// Fused MFMA GEMM + LSTM (mid levels 32..512).  32 nodes/block, grid (B/32, J).
__global__ __launch_bounds__(256) void gemm_lstm_kernel(
    const int* __restrict__ a_idx, const int* __restrict__ b_idx,
    const int* __restrict__ types, float* __restrict__ out,
    const short* __restrict__ Whi, const short* __restrict__ Wlo,
    const float* __restrict__ proj, float* __restrict__ C256,
    short* __restrict__ Hsplit, int node_base, int Jc) {
    __shared__ short Ahi[2][16][64][8];   // 32 KB
    __shared__ short Alo[2][16][64][8];   // 32 KB
    __shared__ int sA[32], sB[32], sT[32];
    int t = threadIdx.x;
    int node0 = node_base + blockIdx.x * 32;
    if (t < 32) {
        sA[t] = a_idx[node0 + t];
        sB[t] = b_idx[node0 + t];
        sT[t] = types[node0 + t];
    }
    __syncthreads();

#pragma unroll
    for (int it = 0; it < 8; ++it) {
        int c = it * 256 + t;
        int mt = c >> 10;
        int kt = (c >> 6) & 15;
        int lane = c & 63;
        int m_loc = mt * 16 + (lane & 15);
        int k0 = kt * 32 + (lane >> 4) * 8;
        int child = (k0 < 256) ? sA[m_loc] : sB[m_loc];
        const short* src = Hsplit + (size_t)child * 512 + (k0 & 255);
        *(bf16x8*)&Ahi[mt][kt][lane][0] = *(const bf16x8*)src;
        *(bf16x8*)&Alo[mt][kt][lane][0] = *(const bf16x8*)(src + 256);
    }
    __syncthreads();

    int w = t >> 6;
    int lane = t & 63;
    int jsteps = Jc >> 4;
    int jbase = blockIdx.y * Jc;

    auto epilogue = [&](int j0, f32x4 (&acc)[4][2]) {
        int j = j0 + (lane & 15);
        int jc = j & 255;
        bool fh = (j < 256);
#pragma unroll
        for (int mt = 0; mt < 2; ++mt) {
            int mrow = mt * 16 + (lane >> 4) * 4;
#pragma unroll
            for (int r = 0; r < 4; ++r) {
                int m_loc = mrow + r;
                int node = node0 + m_loc;
                const float* p = proj + (size_t)sT[m_loc] * 2048 + j;
                float gi = acc[0][mt][r] + p[0];
                float gf = acc[1][mt][r] + p[512];
                float gg = acc[2][mt][r] + p[1024];
                float go = acc[3][mt][r] + p[1536];
                int child = fh ? sA[m_loc] : sB[m_loc];
                float c = C256[(size_t)child * 256 + jc];
                float cn = sigf(gf) * c + sigf(gi) * tanhfast(gg);
                float hn = sigf(go) * tanhfast(cn);
                out[(size_t)node * 512 + j] = hn;
                if (fh) {
                    C256[(size_t)node * 256 + j] = cn;
                    short hi = bf_hi(hn);
                    Hsplit[(size_t)node * 512 + j] = hi;
                    Hsplit[(size_t)node * 512 + 256 + j] = bf_hi(hn - bf_f(hi));
                }
            }
        }
    };

    if (jsteps >= 4) {
        for (int js = w; js < jsteps; js += 4) {
            int j0 = jbase + js * 16;
            f32x4 acc[4][2];
#pragma unroll
            for (int q = 0; q < 4; ++q)
#pragma unroll
                for (int mt = 0; mt < 2; ++mt) acc[q][mt] = (f32x4){0.f, 0.f, 0.f, 0.f};
            int nt0 = j0 >> 4;
#pragma unroll 4
            for (int kt = 0; kt < 16; ++kt) {
                bf16x8 ah0 = *(const bf16x8*)&Ahi[0][kt][lane][0];
                bf16x8 al0 = *(const bf16x8*)&Alo[0][kt][lane][0];
                bf16x8 ah1 = *(const bf16x8*)&Ahi[1][kt][lane][0];
                bf16x8 al1 = *(const bf16x8*)&Alo[1][kt][lane][0];
#pragma unroll
                for (int q = 0; q < 4; ++q) {
                    int ntile = q * 32 + nt0;
                    size_t off = ((size_t)(ntile * 16 + kt) * 64 + lane) * 8;
                    bf16x8 bh = *(const bf16x8*)(Whi + off);
                    bf16x8 bl = *(const bf16x8*)(Wlo + off);
                    acc[q][0] = __builtin_amdgcn_mfma_f32_16x16x32_bf16(ah0, bh, acc[q][0], 0, 0, 0);
                    acc[q][0] = __builtin_amdgcn_mfma_f32_16x16x32_bf16(ah0, bl, acc[q][0], 0, 0, 0);
                    acc[q][0] = __builtin_amdgcn_mfma_f32_16x16x32_bf16(al0, bh, acc[q][0], 0, 0, 0);
                    acc[q][1] = __builtin_amdgcn_mfma_f32_16x16x32_bf16(ah1, bh, acc[q][1], 0, 0, 0);
                    acc[q][1] = __builtin_amdgcn_mfma_f32_16x16x32_bf16(ah1, bl, acc[q][1], 0, 0, 0);
                    acc[q][1] = __builtin_amdgcn_mfma_f32_16x16x32_bf16(al1, bh, acc[q][1], 0, 0, 0);
                }
            }
            epilogue(j0, acc);
        }
    } else {
        int js = w & 1;
        int khalf = w >> 1;
        int j0 = jbase + js * 16;
        f32x4 acc[4][2];
#pragma unroll
        for (int q = 0; q < 4; ++q)
#pragma unroll
            for (int mt = 0; mt < 2; ++mt) acc[q][mt] = (f32x4){0.f, 0.f, 0.f, 0.f};
        int nt0 = j0 >> 4;
        int kt0 = khalf * 8;
#pragma unroll 4
        for (int kt = kt0; kt < kt0 + 8; ++kt) {
            bf16x8 ah0 = *(const bf16x8*)&Ahi[0][kt][lane][0];
            bf16x8 al0 = *(const bf16x8*)&Alo[0][kt][lane][0];
            bf16x8 ah1 = *(const bf16x8*)&Ahi[1][kt][lane][0];
            bf16x8 al1 = *(const bf16x8*)&Alo[1][kt][lane][0];
#pragma unroll
            for (int q = 0; q < 4; ++q) {
                int ntile = q * 32 + nt0;
                size_t off = ((size_t)(ntile * 16 + kt) * 64 + lane) * 8;
                bf16x8 bh = *(const bf16x8*)(Whi + off);
                bf16x8 bl = *(const bf16x8*)(Wlo + off);
                acc[q][0] = __builtin_amdgcn_mfma_f32_16x16x32_bf16(ah0, bh, acc[q][0], 0, 0, 0);
                acc[q][0] = __builtin_amdgcn_mfma_f32_16x16x32_bf16(ah0, bl, acc[q][0], 0, 0, 0);
                acc[q][0] = __builtin_amdgcn_mfma_f32_16x16x32_bf16(al0, bh, acc[q][0], 0, 0, 0);
                acc[q][1] = __builtin_amdgcn_mfma_f32_16x16x32_bf16(ah1, bh, acc[q][1], 0, 0, 0);
                acc[q][1] = __builtin_amdgcn_mfma_f32_16x16x32_bf16(ah1, bl, acc[q][1], 0, 0, 0);
                acc[q][1] = __builtin_amdgcn_mfma_f32_16x16x32_bf16(al1, bh, acc[q][1], 0, 0, 0);
            }
        }
        __syncthreads();
        float* xch = (float*)&Ahi[0][0][0][0];
        if (khalf == 1) {
#pragma unroll
            for (int q = 0; q < 4; ++q)
#pragma unroll
                for (int mt = 0; mt < 2; ++mt)
                    *(f32x4*)&xch[(((q * 2 + mt) * 128) + js * 64 + lane) * 4] = acc[q][mt];
        }
        __syncthreads();
        if (khalf == 0) {
#pragma unroll
            for (int q = 0; q < 4; ++q)
#pragma unroll
                for (int mt = 0; mt < 2; ++mt) {
                    f32x4 o = *(const f32x4*)&xch[(((q * 2 + mt) * 128) + js * 64 + lane) * 4];
                    acc[q][mt] += o;
                }
            epilogue(j0, acc);
        }
    }
}

// ---------------------------------------------------------------------------
// Small levels (B <= 16): smallv2. grid (8 y, 8 z), block 256.
// Thread t: W row r = y*256 + t, k in [z*64, z*64+64) -- reconstructed from
// the packed bf16 hi/lo tables into 64 VGPRs (W read ONCE per level, 4 MB).
// h-slices for all B nodes staged in LDS (broadcast reads). Writes part[]
// in the layout small_combine_kernel already consumes.
// ---------------------------------------------------------------------------
__global__ __launch_bounds__(256) void smallv2_gemm_kernel(
    const int* __restrict__ a_idx, const int* __restrict__ b_idx,
    const float* __restrict__ out, const short* __restrict__ Whi,
    float* __restrict__ part, int node_base, int B) {
    __shared__ float hs[16][64];   // 4 KB
    const short* Wlo = Whi + 1048576;

    int t = threadIdx.x;
    int y = blockIdx.x, z = blockIdx.y;
    int r = y * 256 + t;
    int kbase = z * 64;

    // stage h[n][0..64) for all B nodes: B*16 float4 loads
    if (t < B * 16) {
        int n = t >> 4;
        int f4 = t & 15;
        int node = node_base + n;
        int child = (kbase < 256) ? a_idx[node] : b_idx[node];
        float4 v = ((const float4*)(out + (size_t)child * 512 + (kbase & 255)))[f4];
        *(float4*)&hs[n][f4 * 4] = v;
    }
    __syncthreads();

    // load my W row slice into regs: 8 pieces of 8 (hi+lo reconstruct)
    float wv[64];
#pragma unroll
    for (int u = 0; u < 8; ++u) {
        int k = kbase + u * 8;
        int kt = k >> 5;
        int sub = (k >> 3) & 3;
        size_t off = ((size_t)((r >> 4) * 16 + kt) * 64 + (sub << 4) + (r & 15)) * 8;
        bf16x8 hi = *(const bf16x8*)(Whi + off);
        bf16x8 lo = *(const bf16x8*)(Wlo + off);
#pragma unroll
        for (int e = 0; e < 8; ++e)
            wv[u * 8 + e] = bf_f(hi[e]) + bf_f(lo[e]);
    }

    for (int n = 0; n < B; ++n) {
        float acc = 0.f;
#pragma unroll
        for (int k = 0; k < 64; ++k) acc += wv[k] * hs[n][k];
        part[((size_t)z * B + n) * 2048 + r] = acc;
    }
}

// combine K-partials + LSTM.  grid (B*2), block 256
__global__ void small_combine_kernel(
    const int* __restrict__ a_idx, const int* __restrict__ b_idx,
    const int* __restrict__ types, const float* __restrict__ part,
    const float* __restrict__ proj, float* __restrict__ C256,
    short* __restrict__ Hsplit, float* __restrict__ out, int node_base, int B) {
    int bi = blockIdx.x;
    int n = bi >> 1;
    int j = ((bi & 1) << 8) + threadIdx.x;
    int node = node_base + n;
    float g[4] = {0.f, 0.f, 0.f, 0.f};
    for (int z = 0; z < 8; ++z) {
        const float* p = part + ((size_t)z * B + n) * 2048;
#pragma unroll
        for (int q = 0; q < 4; ++q) g[q] += p[q * 512 + j];
    }
    const float* p = proj + (size_t)types[node] * 2048 + j;
    float gi = g[0] + p[0];
    float gf = g[1] + p[512];
    float gg = g[2] + p[1024];
    float go = g[3] + p[1536];
    int child = (j < 256) ? a_idx[node] : b_idx[node];
    float c = C256[(size_t)child * 256 + (j & 255)];
    float cn = sigf(gf) * c + sigf(gi) * tanhfast(gg);
    float hn = sigf(go) * tanhfast(cn);
    out[(size_t)node * 512 + j] = hn;
    if (j < 256) {
        C256[(size_t)node * 256 + j] = cn;
        short hi = bf_hi(hn);
        Hsplit[(size_t)node * 512 + j] = hi;
        Hsplit[(size_t)node * 512 + 256 + j] = bf_hi(hn - bf_f(hi));
    }
}

extern "C" void kernel_launch(void* const* d_in, const int* in_sizes, int n_in,
                              void* d_out, int out_size, void* d_ws, size_t ws_size,
                              hipStream_t stream) {
    const int* types = (const int*)d_in[0];
    const int* a_idx = (const int*)d_in[1];
    const int* b_idx = (const int*)d_in[2];
    const float* emb = (const float*)d_in[3];
    const float* W_ih = (const float*)d_in[4];
    const float* W_hh = (const float*)d_in[5];
    const float* b_ih = (const float*)d_in[6];
    const float* b_hh = (const float*)d_in[7];
    float* out = (float*)d_out;

    float* ws = (float*)d_ws;
    float* proj = ws;                               // 65536 floats (256 KB)
    float* C256 = ws + 65536;                       // 8388352 floats (32 MB)
    short* Hsplit = (short*)(C256 + 8388352);       // 32767*512 shorts (32 MB)
    short* Whi = Hsplit + 16777216;                 // 2048*512 shorts (2 MB); MUST stay
    short* Wlo = Whi + 1048576;                     // contiguous after Hsplit (WOFF)
    float* part = (float*)(Wlo + 1048576);          // 8*16*2048 floats (1 MB)
    // total ws use ~69.3 MB

    proj_kernel<<<256, 256, 0, stream>>>(emb, W_ih, b_ih, b_hh, proj);
    wpack_kernel<<<512, 256, 0, stream>>>(W_hh, Whi, Wlo);
    leaf_kernel<<<32768, 256, 0, stream>>>(types, proj, out, C256, Hsplit);

    for (int d = 13; d >= 0; --d) {
        int base = (1 << d) - 1;
        int B = 1 << d;
        if (B >= 1024) {
            int X = B / 128;
            big_gemm_lstm_kernel<<<X * 16, 256, 0, stream>>>(
                a_idx, b_idx, types, out, proj, C256, Hsplit, base);
        } else if (B >= 32) {
            int bx = B / 32;
            int J = 2;
            while (bx * J < 512 && J < 16) J <<= 1;
            gemm_lstm_kernel<<<dim3(bx, J), 256, 0, stream>>>(
                a_idx, b_idx, types, out, Whi, Wlo, proj, C256, Hsplit, base, 512 / J);
        } else {
            smallv2_gemm_kernel<<<dim3(8, 8), 256, 0, stream>>>(
                a_idx, b_idx, out, Whi, part, base, B);
            small_combine_kernel<<<B * 2, 256, 0, stream>>>(
                a_idx, b_idx, types, part, proj, C256, Hsplit, out, base, B);
        }
    }
}

// Round 11
// 385.127 us; speedup vs baseline: 1.3504x; 1.0437x over previous
//
#include <hip/hip_runtime.h>
#include <hip/hip_bf16.h>

// Tree-LSTM, depth-15 complete binary tree. N=32767, state 2H=512, gates 2048.
// R13 = R12b (best, 402us) + three changes:
//  1. big_v2 XCD swizzle REVERSED: pin x (node-tile) per XCD so the A panel
//     (~1MB/XCD) becomes L2-resident; W (4MB) = exactly one XCD L2.
//     map: xcd=lin&7, g=lin>>3, y=g&15, x=(g>>4)*8+xcd  (bijective, X=8k)
//  2. d10 -> gemm_lstm (512 blocks vs 128 half-idle big blocks)
//  3. leaf kernel: one block per node (16384 blocks), both j-halves per block
// Routing: d13..d11 big_v2; d10..d5 gemm_lstm; d4..d0 smallv2+combine.

#define NNODES 32767

typedef __attribute__((ext_vector_type(8))) short bf16x8;
typedef __attribute__((ext_vector_type(4))) float f32x4;

typedef const __attribute__((address_space(1))) void* gptr_t;
typedef __attribute__((address_space(3))) void* lptr_t;

__device__ __forceinline__ float sigf(float x) { return 1.0f / (1.0f + __expf(-x)); }
__device__ __forceinline__ float tanhfast(float x) { return 2.0f / (1.0f + __expf(-2.0f * x)) - 1.0f; }

__device__ __forceinline__ short bf_hi(float x) {
    __hip_bfloat16 h = __float2bfloat16(x);
    return __builtin_bit_cast(short, h);
}
__device__ __forceinline__ float bf_f(short s) {
    __hip_bfloat16 h = __builtin_bit_cast(__hip_bfloat16, s);
    return __bfloat162float(h);
}
__device__ __forceinline__ void split8(const float* src, short* hi, short* lo) {
#pragma unroll
    for (int j = 0; j < 8; ++j) {
        float x = src[j];
        short h = bf_hi(x);
        hi[j] = h;
        lo[j] = bf_hi(x - bf_f(h));
    }
}

// proj[v][r] = dot(emb[v], W_ih[r]) + b_ih[r] + b_hh[r];  grid 256, block 256
__global__ void proj_kernel(const float* __restrict__ emb, const float* __restrict__ W_ih,
                            const float* __restrict__ b_ih, const float* __restrict__ b_hh,
                            float* __restrict__ proj) {
    __shared__ float e[256];
    int v = blockIdx.x >> 3;
    int rc = blockIdx.x & 7;
    int t = threadIdx.x;
    e[t] = emb[v * 256 + t];
    __syncthreads();
    int r = rc * 256 + t;
    const float4* w4 = (const float4*)(W_ih + (size_t)r * 256);
    const float4* e4 = (const float4*)e;
    float acc = 0.f;
#pragma unroll 8
    for (int k = 0; k < 64; ++k) {
        float4 w = w4[k];
        float4 h = e4[k];
        acc += w.x * h.x + w.y * h.y + w.z * h.z + w.w * h.w;
    }
    proj[v * 2048 + r] = acc + b_ih[r] + b_hh[r];
}

// W_hh [2048][512] fp32 -> MFMA B-fragment bf16 hi/lo tables.  grid 512, block 256
__global__ void wpack_kernel(const float* __restrict__ W_hh,
                             short* __restrict__ Whi, short* __restrict__ Wlo) {
    int t = blockIdx.x * 256 + threadIdx.x;
    int lane = t & 63;
    int kt = (t >> 6) & 15;
    int ntile = t >> 10;
    int n = ntile * 16 + (lane & 15);
    int k0 = kt * 32 + (lane >> 4) * 8;
    const float* src = W_hh + (size_t)n * 512 + k0;
    short hi[8], lo[8];
    split8(src, hi, lo);
    *(bf16x8*)(Whi + (size_t)t * 8) = *(bf16x8*)hi;
    *(bf16x8*)(Wlo + (size_t)t * 8) = *(bf16x8*)lo;
}

// leaves: gates = proj[type]. ONE block per node; grid 16384, block 256.
__global__ void leaf_kernel(const int* __restrict__ types, const float* __restrict__ proj,
                            float* __restrict__ out, float* __restrict__ C256,
                            short* __restrict__ Hsplit) {
    int node = 16383 + blockIdx.x;
    int t = threadIdx.x;
    int tt = types[node];
    const float* p = proj + (size_t)tt * 2048;
    // first half j = t (writes out + C256 + Hsplit)
    float gi = p[t];
    float gg = p[1024 + t];
    float go = p[1536 + t];
    float cn = sigf(gi) * tanhfast(gg);
    float hn = sigf(go) * tanhfast(cn);
    out[(size_t)node * 512 + t] = hn;
    C256[(size_t)node * 256 + t] = cn;
    short hi = bf_hi(hn);
    Hsplit[(size_t)node * 512 + t] = hi;
    Hsplit[(size_t)node * 512 + 256 + t] = bf_hi(hn - bf_f(hi));
    // second half j = 256 + t (out only)
    float gi2 = p[256 + t];
    float gg2 = p[1280 + t];
    float go2 = p[1792 + t];
    float cn2 = sigf(gi2) * tanhfast(gg2);
    float hn2 = sigf(go2) * tanhfast(cn2);
    out[(size_t)node * 512 + 256 + t] = hn2;
}

// ---------------------------------------------------------------------------
// Big levels (B >= 2048): big_v2. 256 thr / 4 waves, tile 128 nodes x 128
// gate-rows, BK=32, 2 x 32KB LDS dbuf (2 blocks/CU), reformed contiguous
// A-staging (XOR-swizzled source), counted-vmcnt 2-barrier pipeline.
// XCD swizzle: same-x blocks pinned to one XCD -> A panel L2-resident.
// ---------------------------------------------------------------------------
__global__ __launch_bounds__(256) void big_gemm_lstm_kernel(
    const int* __restrict__ a_idx, const int* __restrict__ b_idx,
    const int* __restrict__ types, float* __restrict__ out,
    const float* __restrict__ proj, float* __restrict__ C256,
    short* __restrict__ Hsplit, int node_base) {
    __shared__ __align__(16) short lds[2][16384];  // 64 KB: 2 x 32 chunks x 512
    __shared__ int sA[128], sB[128], sT[128];

    const unsigned WOFF = 16777216u;  // Whi - Hsplit in shorts (ws layout)

    int t = threadIdx.x;
    int lin = blockIdx.x;
    // x-pinned-per-XCD swizzle (round-robin dispatch: xcd = lin & 7):
    // all 16 y-blocks of one x share an XCD -> A ~1MB L2-resident, W 4MB = L2.
    // Bijective for X = 8,16,32,64 (all big levels).
    int xcd = lin & 7;
    int g = lin >> 3;
    int y = g & 15;
    int x = (g >> 4) * 8 + xcd;
    int node0 = node_base + x * 128;
    int j0 = y * 32;

    if (t < 128) {
        sA[t] = a_idx[node0 + t];
        sB[t] = b_idx[node0 + t];
        sT[t] = types[node0 + t];
    }
    __syncthreads();

    int w = t >> 6, lane = t & 63;
    int wm = w >> 1, wn = w & 1;

    unsigned b0[8], b1[8], sk;
    if (w < 2) {
        sk = 32u;
#pragma unroll
        for (int i = 0; i < 8; ++i) {
            int ca = w * 8 + i;
            int rl = lane >> 3;
            int r_loc = ca * 8 + rl;
            int j = (lane & 7) ^ rl;
            unsigned ks = (unsigned)(j >> 2) * 256u + (unsigned)(j & 3) * 8u;
            b0[i] = (unsigned)sA[r_loc] * 512u + ks;
            b1[i] = (unsigned)sB[r_loc] * 512u + ks;
        }
    } else {
        sk = 512u;
#pragma unroll
        for (int i = 0; i < 8; ++i) {
            int cc = (w - 2) * 8 + i;
            int nt = cc >> 1, part = cc & 1;
            int q = nt >> 1, sub = nt & 1;
            unsigned ntg = (unsigned)(q * 32 + y * 2 + sub);
            b0[i] = WOFF + ntg * 8192u + (unsigned)part * 1048576u + (unsigned)lane * 8u;
            b1[i] = b0[i] + 4096u;
        }
    }

    f32x4 acc[4][4];
#pragma unroll
    for (int i = 0; i < 4; ++i)
#pragma unroll
        for (int q = 0; q < 4; ++q) acc[i][q] = (f32x4){0.f, 0.f, 0.f, 0.f};

    auto stage = [&](int kt, int buf) {
#pragma unroll
        for (int i = 0; i < 8; ++i) {
            unsigned off = ((kt < 8) ? b0[i] : b1[i]) + (unsigned)(kt & 7) * sk;
            const short* gsrc = Hsplit + off;
            short* ldst = &lds[buf][(w * 8 + i) * 512];
            __builtin_amdgcn_global_load_lds((gptr_t)gsrc, (lptr_t)ldst, 16, 0, 0);
        }
    };

    auto compute = [&](int buf) {
        const short* L = lds[buf];
        int s = lane >> 4;
        bf16x8 ah[4], al[4];
#pragma unroll
        for (int i = 0; i < 4; ++i) {
            int m_loc = (wm * 4 + i) * 16 + (lane & 15);
            int ch = m_loc >> 3;
            int r = m_loc & 7;
            const short* base = L + ch * 512 + r * 64;
            ah[i] = *(const bf16x8*)&base[(s ^ r) * 8];
            al[i] = *(const bf16x8*)&base[((4 + s) ^ r) * 8];
        }
        __builtin_amdgcn_s_setprio(1);
#pragma unroll
        for (int q = 0; q < 4; ++q) {
            int nt = q * 2 + wn;
            bf16x8 bh = *(const bf16x8*)&L[(16 + nt * 2) * 512 + lane * 8];
            bf16x8 bl = *(const bf16x8*)&L[(17 + nt * 2) * 512 + lane * 8];
#pragma unroll
            for (int i = 0; i < 4; ++i) {
                acc[i][q] = __builtin_amdgcn_mfma_f32_16x16x32_bf16(ah[i], bh, acc[i][q], 0, 0, 0);
                acc[i][q] = __builtin_amdgcn_mfma_f32_16x16x32_bf16(ah[i], bl, acc[i][q], 0, 0, 0);
                acc[i][q] = __builtin_amdgcn_mfma_f32_16x16x32_bf16(al[i], bh, acc[i][q], 0, 0, 0);
            }
        }
        __builtin_amdgcn_s_setprio(0);
    };

    stage(0, 0);
    int cur = 0;
#pragma unroll 1
    for (int kt = 0; kt < 16; ++kt) {
        __builtin_amdgcn_s_barrier();
        if (kt < 15) stage(kt + 1, cur ^ 1);
        if (kt < 15) {
            asm volatile("s_waitcnt vmcnt(8)" ::: "memory");
        } else {
            asm volatile("s_waitcnt vmcnt(0)" ::: "memory");
        }
        __builtin_amdgcn_s_barrier();
        compute(cur);
        cur ^= 1;
    }

    int j = j0 + wn * 16 + (lane & 15);
    bool fh = (j < 256);
    int jc = j & 255;
#pragma unroll
    for (int i = 0; i < 4; ++i) {
        int mrow = wm * 64 + i * 16 + (lane >> 4) * 4;
#pragma unroll
        for (int r = 0; r < 4; ++r) {
            int m_loc = mrow + r;
            int node = node0 + m_loc;
            const float* p = proj + (size_t)sT[m_loc] * 2048 + j;
            float gi = acc[i][0][r] + p[0];
            float gf = acc[i][1][r] + p[512];
            float gg = acc[i][2][r] + p[1024];
            float go = acc[i][3][r] + p[1536];
            int child = fh ? sA[m_loc] : sB[m_loc];
            float c = C256[(size_t)child * 256 + jc];
            float cn = sigf(gf) * c + sigf(gi) * tanhfast(gg);
            float hn = sigf(go) * tanhfast(cn);
            out[(size_t)node * 512 + j] = hn;
            if (fh) {
                C256[(size_t)node * 256 + j] = cn;
                short hi = bf_hi(hn);
                Hsplit[(size_t)node * 512 + j] = hi;
                Hsplit[(size_t)node * 512 + 256 + j] = bf_hi(hn - bf_f(hi));
            }
        }
    }
}

// Fused MFMA GEMM + LSTM (mid levels 32..1024).  32 nodes/block, grid (B/32, J).
__global__ __launch_bounds__(256) void gemm_lstm_kernel(
    const int* __restrict__ a_idx, const int* __restrict__ b_idx,
    const int* __restrict__ types, float* __restrict__ out,
    const short* __restrict__ Whi, const short* __restrict__ Wlo,
    const float* __restrict__ proj, float* __restrict__ C256,
    short* __restrict__ Hsplit, int node_base, int Jc) {
    __shared__ short Ahi[2][16][64][8];   // 32 KB
    __shared__ short Alo[2][16][64][8];   // 32 KB
    __shared__ int sA[32], sB[32], sT[32];
    int t = threadIdx.x;
    int node0 = node_base + blockIdx.x * 32;
    if (t < 32) {
        sA[t] = a_idx[node0 + t];
        sB[t] = b_idx[node0 + t];
        sT[t] = types[node0 + t];
    }
    __syncthreads();

#pragma unroll
    for (int it = 0; it < 8; ++it) {
        int c = it * 256 + t;
        int mt = c >> 10;
        int kt = (c >> 6) & 15;
        int lane = c & 63;
        int m_loc = mt * 16 + (lane & 15);
        int k0 = kt * 32 + (lane >> 4) * 8;
        int child = (k0 < 256) ? sA[m_loc] : sB[m_loc];
        const short* src = Hsplit + (size_t)child * 512 + (k0 & 255);
        *(bf16x8*)&Ahi[mt][kt][lane][0] = *(const bf16x8*)src;
        *(bf16x8*)&Alo[mt][kt][lane][0] = *(const bf16x8*)(src + 256);
    }
    __syncthreads();

    int w = t >> 6;
    int lane = t & 63;
    int jsteps = Jc >> 4;
    int jbase = blockIdx.y * Jc;

    auto epilogue = [&](int j0, f32x4 (&acc)[4][2]) {
        int j = j0 + (lane & 15);
        int jc = j & 255;
        bool fh = (j < 256);
#pragma unroll
        for (int mt = 0; mt < 2; ++mt) {
            int mrow = mt * 16 + (lane >> 4) * 4;
#pragma unroll
            for (int r = 0; r < 4; ++r) {
                int m_loc = mrow + r;
                int node = node0 + m_loc;
                const float* p = proj + (size_t)sT[m_loc] * 2048 + j;
                float gi = acc[0][mt][r] + p[0];
                float gf = acc[1][mt][r] + p[512];
                float gg = acc[2][mt][r] + p[1024];
                float go = acc[3][mt][r] + p[1536];
                int child = fh ? sA[m_loc] : sB[m_loc];
                float c = C256[(size_t)child * 256 + jc];
                float cn = sigf(gf) * c + sigf(gi) * tanhfast(gg);
                float hn = sigf(go) * tanhfast(cn);
                out[(size_t)node * 512 + j] = hn;
                if (fh) {
                    C256[(size_t)node * 256 + j] = cn;
                    short hi = bf_hi(hn);
                    Hsplit[(size_t)node * 512 + j] = hi;
                    Hsplit[(size_t)node * 512 + 256 + j] = bf_hi(hn - bf_f(hi));
                }
            }
        }
    };

    if (jsteps >= 4) {
        for (int js = w; js < jsteps; js += 4) {
            int j0 = jbase + js * 16;
            f32x4 acc[4][2];
#pragma unroll
            for (int q = 0; q < 4; ++q)
#pragma unroll
                for (int mt = 0; mt < 2; ++mt) acc[q][mt] = (f32x4){0.f, 0.f, 0.f, 0.f};
            int nt0 = j0 >> 4;
#pragma unroll 4
            for (int kt = 0; kt < 16; ++kt) {
                bf16x8 ah0 = *(const bf16x8*)&Ahi[0][kt][lane][0];
                bf16x8 al0 = *(const bf16x8*)&Alo[0][kt][lane][0];
                bf16x8 ah1 = *(const bf16x8*)&Ahi[1][kt][lane][0];
                bf16x8 al1 = *(const bf16x8*)&Alo[1][kt][lane][0];
#pragma unroll
                for (int q = 0; q < 4; ++q) {
                    int ntile = q * 32 + nt0;
                    size_t off = ((size_t)(ntile * 16 + kt) * 64 + lane) * 8;
                    bf16x8 bh = *(const bf16x8*)(Whi + off);
                    bf16x8 bl = *(const bf16x8*)(Wlo + off);
                    acc[q][0] = __builtin_amdgcn_mfma_f32_16x16x32_bf16(ah0, bh, acc[q][0], 0, 0, 0);
                    acc[q][0] = __builtin_amdgcn_mfma_f32_16x16x32_bf16(ah0, bl, acc[q][0], 0, 0, 0);
                    acc[q][0] = __builtin_amdgcn_mfma_f32_16x16x32_bf16(al0, bh, acc[q][0], 0, 0, 0);
                    acc[q][1] = __builtin_amdgcn_mfma_f32_16x16x32_bf16(ah1, bh, acc[q][1], 0, 0, 0);
                    acc[q][1] = __builtin_amdgcn_mfma_f32_16x16x32_bf16(ah1, bl, acc[q][1], 0, 0, 0);
                    acc[q][1] = __builtin_amdgcn_mfma_f32_16x16x32_bf16(al1, bh, acc[q][1], 0, 0, 0);
                }
            }
            epilogue(j0, acc);
        }
    } else {
        int js = w & 1;
        int khalf = w >> 1;
        int j0 = jbase + js * 16;
        f32x4 acc[4][2];
#pragma unroll
        for (int q = 0; q < 4; ++q)
#pragma unroll
            for (int mt = 0; mt < 2; ++mt) acc[q][mt] = (f32x4){0.f, 0.f, 0.f, 0.f};
        int nt0 = j0 >> 4;
        int kt0 = khalf * 8;
#pragma unroll 4
        for (int kt = kt0; kt < kt0 + 8; ++kt) {
            bf16x8 ah0 = *(const bf16x8*)&Ahi[0][kt][lane][0];
            bf16x8 al0 = *(const bf16x8*)&Alo[0][kt][lane][0];
            bf16x8 ah1 = *(const bf16x8*)&Ahi[1][kt][lane][0];
            bf16x8 al1 = *(const bf16x8*)&Alo[1][kt][lane][0];
#pragma unroll
            for (int q = 0; q < 4; ++q) {
                int ntile = q * 32 + nt0;
                size_t off = ((size_t)(ntile * 16 + kt) * 64 + lane) * 8;
                bf16x8 bh = *(const bf16x8*)(Whi + off);
                bf16x8 bl = *(const bf16x8*)(Wlo + off);
                acc[q][0] = __builtin_amdgcn_mfma_f32_16x16x32_bf16(ah0, bh, acc[q][0], 0, 0, 0);
                acc[q][0] = __builtin_amdgcn_mfma_f32_16x16x32_bf16(ah0, bl, acc[q][0], 0, 0, 0);
                acc[q][0] = __builtin_amdgcn_mfma_f32_16x16x32_bf16(al0, bh, acc[q][0], 0, 0, 0);
                acc[q][1] = __builtin_amdgcn_mfma_f32_16x16x32_bf16(ah1, bh, acc[q][1], 0, 0, 0);
                acc[q][1] = __builtin_amdgcn_mfma_f32_16x16x32_bf16(ah1, bl, acc[q][1], 0, 0, 0);
                acc[q][1] = __builtin_amdgcn_mfma_f32_16x16x32_bf16(al1, bh, acc[q][1], 0, 0, 0);
            }
        }
        __syncthreads();
        float* xch = (float*)&Ahi[0][0][0][0];
        if (khalf == 1) {
#pragma unroll
            for (int q = 0; q < 4; ++q)
#pragma unroll
                for (int mt = 0; mt < 2; ++mt)
                    *(f32x4*)&xch[(((q * 2 + mt) * 128) + js * 64 + lane) * 4] = acc[q][mt];
        }
        __syncthreads();
        if (khalf == 0) {
#pragma unroll
            for (int q = 0; q < 4; ++q)
#pragma unroll
                for (int mt = 0; mt < 2; ++mt) {
                    f32x4 o = *(const f32x4*)&xch[(((q * 2 + mt) * 128) + js * 64 + lane) * 4];
                    acc[q][mt] += o;
                }
            epilogue(j0, acc);
        }
    }
}

// ---------------------------------------------------------------------------
// Small levels (B <= 16): smallv2 (W read once per level from packed tables).
// ---------------------------------------------------------------------------
__global__ __launch_bounds__(256) void smallv2_gemm_kernel(
    const int* __restrict__ a_idx, const int* __restrict__ b_idx,
    const float* __restrict__ out, const short* __restrict__ Whi,
    float* __restrict__ part, int node_base, int B) {
    __shared__ float hs[16][64];   // 4 KB
    const short* Wlo = Whi + 1048576;

    int t = threadIdx.x;
    int y = blockIdx.x, z = blockIdx.y;
    int r = y * 256 + t;
    int kbase = z * 64;

    if (t < B * 16) {
        int n = t >> 4;
        int f4 = t & 15;
        int node = node_base + n;
        int child = (kbase < 256) ? a_idx[node] : b_idx[node];
        float4 v = ((const float4*)(out + (size_t)child * 512 + (kbase & 255)))[f4];
        *(float4*)&hs[n][f4 * 4] = v;
    }
    __syncthreads();

    float wv[64];
#pragma unroll
    for (int u = 0; u < 8; ++u) {
        int k = kbase + u * 8;
        int kt = k >> 5;
        int sub = (k >> 3) & 3;
        size_t off = ((size_t)((r >> 4) * 16 + kt) * 64 + (sub << 4) + (r & 15)) * 8;
        bf16x8 hi = *(const bf16x8*)(Whi + off);
        bf16x8 lo = *(const bf16x8*)(Wlo + off);
#pragma unroll
        for (int e = 0; e < 8; ++e)
            wv[u * 8 + e] = bf_f(hi[e]) + bf_f(lo[e]);
    }

    for (int n = 0; n < B; ++n) {
        float acc = 0.f;
#pragma unroll
        for (int k = 0; k < 64; ++k) acc += wv[k] * hs[n][k];
        part[((size_t)z * B + n) * 2048 + r] = acc;
    }
}

// combine K-partials + LSTM.  grid (B*2), block 256
__global__ void small_combine_kernel(
    const int* __restrict__ a_idx, const int* __restrict__ b_idx,
    const int* __restrict__ types, const float* __restrict__ part,
    const float* __restrict__ proj, float* __restrict__ C256,
    short* __restrict__ Hsplit, float* __restrict__ out, int node_base, int B) {
    int bi = blockIdx.x;
    int n = bi >> 1;
    int j = ((bi & 1) << 8) + threadIdx.x;
    int node = node_base + n;
    float g[4] = {0.f, 0.f, 0.f, 0.f};
    for (int z = 0; z < 8; ++z) {
        const float* p = part + ((size_t)z * B + n) * 2048;
#pragma unroll
        for (int q = 0; q < 4; ++q) g[q] += p[q * 512 + j];
    }
    const float* p = proj + (size_t)types[node] * 2048 + j;
    float gi = g[0] + p[0];
    float gf = g[1] + p[512];
    float gg = g[2] + p[1024];
    float go = g[3] + p[1536];
    int child = (j < 256) ? a_idx[node] : b_idx[node];
    float c = C256[(size_t)child * 256 + (j & 255)];
    float cn = sigf(gf) * c + sigf(gi) * tanhfast(gg);
    float hn = sigf(go) * tanhfast(cn);
    out[(size_t)node * 512 + j] = hn;
    if (j < 256) {
        C256[(size_t)node * 256 + j] = cn;
        short hi = bf_hi(hn);
        Hsplit[(size_t)node * 512 + j] = hi;
        Hsplit[(size_t)node * 512 + 256 + j] = bf_hi(hn - bf_f(hi));
    }
}

extern "C" void kernel_launch(void* const* d_in, const int* in_sizes, int n_in,
                              void* d_out, int out_size, void* d_ws, size_t ws_size,
                              hipStream_t stream) {
    const int* types = (const int*)d_in[0];
    const int* a_idx = (const int*)d_in[1];
    const int* b_idx = (const int*)d_in[2];
    const float* emb = (const float*)d_in[3];
    const float* W_ih = (const float*)d_in[4];
    const float* W_hh = (const float*)d_in[5];
    const float* b_ih = (const float*)d_in[6];
    const float* b_hh = (const float*)d_in[7];
    float* out = (float*)d_out;

    float* ws = (float*)d_ws;
    float* proj = ws;                               // 65536 floats (256 KB)
    float* C256 = ws + 65536;                       // 8388352 floats (32 MB)
    short* Hsplit = (short*)(C256 + 8388352);       // 32767*512 shorts (32 MB)
    short* Whi = Hsplit + 16777216;                 // 2048*512 shorts (2 MB); MUST stay
    short* Wlo = Whi + 1048576;                     // contiguous after Hsplit (WOFF)
    float* part = (float*)(Wlo + 1048576);          // 8*16*2048 floats (1 MB)
    // total ws use ~69.3 MB

    proj_kernel<<<256, 256, 0, stream>>>(emb, W_ih, b_ih, b_hh, proj);
    wpack_kernel<<<512, 256, 0, stream>>>(W_hh, Whi, Wlo);
    leaf_kernel<<<16384, 256, 0, stream>>>(types, proj, out, C256, Hsplit);

    for (int d = 13; d >= 0; --d) {
        int base = (1 << d) - 1;
        int B = 1 << d;
        if (B >= 2048) {
            int X = B / 128;
            big_gemm_lstm_kernel<<<X * 16, 256, 0, stream>>>(
                a_idx, b_idx, types, out, proj, C256, Hsplit, base);
        } else if (B >= 32) {
            int bx = B / 32;
            int J = 2;
            while (bx * J < 512 && J < 16) J <<= 1;
            gemm_lstm_kernel<<<dim3(bx, J), 256, 0, stream>>>(
                a_idx, b_idx, types, out, Whi, Wlo, proj, C256, Hsplit, base, 512 / J);
        } else {
            smallv2_gemm_kernel<<<dim3(8, 8), 256, 0, stream>>>(
                a_idx, b_idx, out, Whi, part, base, B);
            small_combine_kernel<<<B * 2, 256, 0, stream>>>(
                a_idx, b_idx, types, part, proj, C256, Hsplit, out, base, B);
        }
    }
}